// Round 1
// baseline (3350.790 us; speedup 1.0000x reference)
//
#include <hip/hip_runtime.h>
#include <math.h>

#define B_ 128
#define T_ 512
#define C_ 21
#define L_ 63
#define D_ 512
#define H_ 8
#define DH_ 64
#define MODES_ 31
#define FF_ 2048
#define P_ 96
#define KMA 25
#define PAD 12
#define NOUT (P_*C_)      /* 2016 */
#define KHEAD (L_*D_)     /* 32256 */
#define ML (B_*L_)        /* 8064 rows */

// ---------------- series_decomp on raw input (T=512) ----------------
__global__ void decomp_input_k(const float* __restrict__ x, float* __restrict__ seas,
                               float* __restrict__ trend) {
    int idx = blockIdx.x * 256 + threadIdx.x;
    if (idx >= B_*T_*C_) return;
    int c = idx % C_; int r = idx / C_; int t = r % T_; int b = r / T_;
    const float* xb = x + (size_t)b * T_ * C_ + c;
    float s = 0.f;
    #pragma unroll
    for (int i = -PAD; i <= PAD; ++i) {
        int tt = t + i; tt = tt < 0 ? 0 : (tt > T_-1 ? T_-1 : tt);
        s += xb[(size_t)tt * C_];
    }
    float mean = s * (1.f / KMA);
    float xv = xb[(size_t)t * C_];
    seas[idx]  = xv - mean;
    trend[idx] = mean;
}

// --------- trend linear head; also writes trend_b + head_b so head kernel can just += ---------
__global__ void trend_head_k(const float* __restrict__ trend, const float* __restrict__ tW,
                             const float* __restrict__ tb, const float* __restrict__ hb,
                             float* __restrict__ out) {
    int idx = blockIdx.x * 256 + threadIdx.x; // (b,p,c)
    if (idx >= B_*P_*C_) return;
    int c = idx % C_; int r = idx / C_; int p = r % P_; int b = r / P_;
    const float* tr = trend + (size_t)b * T_ * C_ + c;
    const float* w  = tW + (size_t)p * T_;
    float s = 0.f;
    for (int l = 0; l < T_; ++l) s += tr[(size_t)l * C_] * w[l];
    out[idx] = s + tb[p] + hb[p*C_ + c];
}

// ---------------- gather patches: xp[b,n,c*16+j] = seas[b, 8n+j, c] ----------------
__global__ void patches_k(const float* __restrict__ seas, float* __restrict__ xp) {
    int idx = blockIdx.x * 256 + threadIdx.x;
    if (idx >= B_*L_*336) return;
    int col = idx % 336; int r = idx / 336; int n = r % L_; int b = r / L_;
    int c = col >> 4; int j = col & 15;
    xp[idx] = seas[((size_t)b * T_ + 8*n + j) * C_ + c];
}

// ---------------- DFT tables, arg reduced mod 63 ----------------
__global__ void tables_k(float* __restrict__ cosT, float* __restrict__ sinT) {
    int idx = blockIdx.x * 64 + threadIdx.x;
    if (idx >= MODES_ * L_) return;
    int m = idx / L_, l = idx % L_;
    int r = (m * l) % L_;
    double a = 6.283185307179586476925286766559 * (double)r / 63.0;
    cosT[idx] = (float)cos(a);
    sinT[idx] = (float)sin(a);
}

// ---------------- generic tiled GEMM: C = A(M,K) @ W(N,K)^T + bias, optional exact GELU ----------------
// requires M%64==0, N%64==0, K%16==0
__global__ __launch_bounds__(256) void gemm_bt(const float* __restrict__ A,
                                               const float* __restrict__ W,
                                               const float* __restrict__ bias,
                                               float* __restrict__ C,
                                               int M, int N, int K, int act) {
    __shared__ float As[16][64];
    __shared__ float Ws[16][64];
    int bm = blockIdx.y, bn = blockIdx.x;
    int t = threadIdx.x;
    int lr = t >> 2;          // 0..63
    int lc = (t & 3) << 2;    // 0,4,8,12
    int tm = (t & 15) << 2;
    int tn = (t >> 4) << 2;
    float acc[4][4] = {};
    const float* Ab = A + (size_t)(bm * 64) * K;
    const float* Wb = W + (size_t)(bn * 64) * K;
    for (int k0 = 0; k0 < K; k0 += 16) {
        float4 a4 = *(const float4*)(Ab + (size_t)lr * K + k0 + lc);
        float4 w4 = *(const float4*)(Wb + (size_t)lr * K + k0 + lc);
        __syncthreads();
        As[lc+0][lr] = a4.x; As[lc+1][lr] = a4.y; As[lc+2][lr] = a4.z; As[lc+3][lr] = a4.w;
        Ws[lc+0][lr] = w4.x; Ws[lc+1][lr] = w4.y; Ws[lc+2][lr] = w4.z; Ws[lc+3][lr] = w4.w;
        __syncthreads();
        #pragma unroll
        for (int kk = 0; kk < 16; ++kk) {
            float4 av = *(const float4*)&As[kk][tm];
            float4 wv = *(const float4*)&Ws[kk][tn];
            float a[4] = {av.x, av.y, av.z, av.w};
            float w[4] = {wv.x, wv.y, wv.z, wv.w};
            #pragma unroll
            for (int i = 0; i < 4; ++i)
                #pragma unroll
                for (int j = 0; j < 4; ++j)
                    acc[i][j] = fmaf(a[i], w[j], acc[i][j]);
        }
    }
    #pragma unroll
    for (int i = 0; i < 4; ++i) {
        int m = bm*64 + tm + i;
        #pragma unroll
        for (int j = 0; j < 4; ++j) {
            int n = bn*64 + tn + j;
            float v = acc[i][j];
            if (bias) v += bias[n];
            if (act == 1) v = 0.5f * v * (1.f + erff(v * 0.70710678118654752f));
            C[(size_t)m * N + n] = v;
        }
    }
}

// ---------------- forward DFT of q (per b,h,e,m) ----------------
__global__ void fftfwd_k(const float* __restrict__ q, const float* __restrict__ cosT,
                         const float* __restrict__ sinT,
                         float* __restrict__ xre, float* __restrict__ xim) {
    int idx = blockIdx.x * 256 + threadIdx.x;
    if (idx >= B_*H_*DH_*MODES_) return;
    int m = idx % MODES_; int r = idx / MODES_;
    int e = r % DH_; r /= DH_; int h = r % H_; int b = r / H_;
    const float* qb = q + (size_t)b * L_ * D_ + h * DH_ + e;
    const float* ct = cosT + m * L_;
    const float* st = sinT + m * L_;
    float re = 0.f, im = 0.f;
    for (int l = 0; l < L_; ++l) {
        float v = qb[(size_t)l * D_];
        re += v * ct[l];
        im -= v * st[l];
    }
    xre[idx] = re; xim[idx] = im;
}

// ---------------- complex mode mixing: out[b,h,f,m] = sum_e x[b,h,e,m] * W[h,e,f,m] ----------------
__global__ __launch_bounds__(256) void modemix_k(const float* __restrict__ xre,
                                                 const float* __restrict__ xim,
                                                 const float* __restrict__ wr,
                                                 const float* __restrict__ wi,
                                                 float* __restrict__ ore,
                                                 float* __restrict__ oim) {
    __shared__ float wrs[64][64];
    __shared__ float wis[64][64];
    int h = blockIdx.x / MODES_, m = blockIdx.x % MODES_;
    int t = threadIdx.x;
    for (int idx = t; idx < 4096; idx += 256) {
        int e = idx >> 6, f = idx & 63;
        size_t wix = (((size_t)(h*64 + e)) * 64 + f) * MODES_ + m;
        wrs[e][f] = wr[wix]; wis[e][f] = wi[wix];
    }
    __syncthreads();
    int f = t & 63; int bg = t >> 6; // 4 b-groups
    for (int b = bg; b < B_; b += 4) {
        const float* xr = xre + ((size_t)(b*H_ + h) * DH_) * MODES_ + m;
        const float* xi = xim + ((size_t)(b*H_ + h) * DH_) * MODES_ + m;
        float ar = 0.f, ai = 0.f;
        for (int e = 0; e < 64; ++e) {
            float xrv = xr[(size_t)e * MODES_], xiv = xi[(size_t)e * MODES_];
            ar += xrv * wrs[e][f] - xiv * wis[e][f];
            ai += xrv * wis[e][f] + xiv * wrs[e][f];
        }
        size_t ox = ((size_t)(b*H_ + h) * DH_ + f) * MODES_ + m;
        ore[ox] = ar; oim[ox] = ai;
    }
}

// ---------------- inverse rfft (drops Im(X0)), writes y in (b,h,f,l) = flat (b,l,d) order ----------------
__global__ void ifft_k(const float* __restrict__ ore, const float* __restrict__ oim,
                       const float* __restrict__ cosT, const float* __restrict__ sinT,
                       float* __restrict__ y) {
    int idx = blockIdx.x * 256 + threadIdx.x;
    if (idx >= B_*H_*DH_*L_) return;
    int l = idx % L_; int r = idx / L_;
    int f = r % DH_; r /= DH_; int h = r % H_; int b = r / H_;
    size_t base = ((size_t)(b*H_ + h) * DH_ + f) * MODES_;
    float s = ore[base];  // Re(X0) only
    for (int m = 1; m < MODES_; ++m) {
        s += 2.f * (ore[base+m] * cosT[m*L_ + l] - oim[base+m] * sinT[m*L_ + l]);
    }
    y[idx] = s * (1.f / 63.f);  // idx == b*32256 + (h*64+f)*63 + l
}

// ---------------- out = (X+Y) - movavg_L(X+Y), window 25, edge pad ----------------
__global__ void decomp_add_k(const float* __restrict__ X, const float* __restrict__ Yv,
                             float* __restrict__ out) {
    int idx = blockIdx.x * 256 + threadIdx.x;
    if (idx >= B_*L_*D_) return;
    int d = idx % D_; int r = idx / D_; int l = r % L_; int b = r / L_;
    const float* xb = X  + (size_t)b * L_ * D_ + d;
    const float* yb = Yv + (size_t)b * L_ * D_ + d;
    float s = 0.f;
    #pragma unroll
    for (int i = -PAD; i <= PAD; ++i) {
        int ll = l + i; ll = ll < 0 ? 0 : (ll > L_-1 ? L_-1 : ll);
        s += xb[(size_t)ll * D_] + yb[(size_t)ll * D_];
    }
    float cur = xb[(size_t)l * D_] + yb[(size_t)l * D_];
    out[idx] = cur - s * (1.f / KMA);
}

// ---------------- layernorm over last dim (512), one wave per row ----------------
__global__ void layernorm_k(const float* __restrict__ X, const float* __restrict__ g,
                            const float* __restrict__ bt, float* __restrict__ Y) {
    int row = blockIdx.x; int t = threadIdx.x;
    const float* x = X + (size_t)row * D_;
    float v[8]; float s = 0.f, s2 = 0.f;
    #pragma unroll
    for (int i = 0; i < 8; ++i) { v[i] = x[t + 64*i]; s += v[i]; s2 += v[i]*v[i]; }
    #pragma unroll
    for (int o = 32; o > 0; o >>= 1) { s += __shfl_down(s, o); s2 += __shfl_down(s2, o); }
    s = __shfl(s, 0); s2 = __shfl(s2, 0);
    float mu = s * (1.f/D_);
    float var = s2 * (1.f/D_) - mu*mu;
    float rs = rsqrtf(var + 1e-5f);
    #pragma unroll
    for (int i = 0; i < 8; ++i) {
        int d = t + 64*i;
        Y[(size_t)row * D_ + d] = (v[i] - mu) * rs * g[d] + bt[d];
    }
}

// ---------------- subtract mean over L axis, per (b,d) ----------------
__global__ void colmean_k(const float* __restrict__ X, float* __restrict__ out) {
    int idx = blockIdx.x * 256 + threadIdx.x;
    if (idx >= B_*D_) return;
    int d = idx % D_, b = idx / D_;
    const float* xb = X + (size_t)b * L_ * D_ + d;
    float s = 0.f;
    for (int l = 0; l < L_; ++l) s += xb[(size_t)l * D_];
    s *= (1.f / L_);
    float* ob = out + (size_t)b * L_ * D_ + d;
    for (int l = 0; l < L_; ++l) ob[(size_t)l * D_] = xb[(size_t)l * D_] - s;
}

// ---------------- transpose enc (B,32256) -> encT (32256,B) ----------------
__global__ void transp_k(const float* __restrict__ X, float* __restrict__ Y) {
    int idx = blockIdx.x * 256 + threadIdx.x;
    if (idx >= B_*KHEAD) return;
    int k = idx % KHEAD, b = idx / KHEAD;
    Y[(size_t)k * B_ + b] = X[idx];
}

// ---------------- head GEMM: out[b,n] += sum_k encT[k,b]*W[n,k]; grid (126 ntiles, 8 kchunks) ----------------
__global__ __launch_bounds__(256) void head_k(const float* __restrict__ encT,
                                              const float* __restrict__ W,
                                              float* __restrict__ out) {
    int b  = threadIdx.x & 127;
    int nh = threadIdx.x >> 7;            // 0/1
    int n0 = blockIdx.x * 16 + nh * 8;
    int k0 = blockIdx.y * 4032, k1 = k0 + 4032;
    float acc[8] = {};
    for (int k = k0; k < k1; k += 4) {
        float e0 = encT[(size_t)(k+0) * B_ + b];
        float e1 = encT[(size_t)(k+1) * B_ + b];
        float e2 = encT[(size_t)(k+2) * B_ + b];
        float e3 = encT[(size_t)(k+3) * B_ + b];
        #pragma unroll
        for (int j = 0; j < 8; ++j) {
            const float4 w = *(const float4*)(W + (size_t)(n0 + j) * KHEAD + k);
            acc[j] += e0*w.x + e1*w.y + e2*w.z + e3*w.w;
        }
    }
    #pragma unroll
    for (int j = 0; j < 8; ++j)
        atomicAdd(&out[(size_t)b * NOUT + n0 + j], acc[j]);
}

extern "C" void kernel_launch(void* const* d_in, const int* in_sizes, int n_in,
                              void* d_out, int out_size, void* d_ws, size_t ws_size,
                              hipStream_t stream) {
    const float* x_enc   = (const float*)d_in[0];
    const float* patch_W = (const float*)d_in[4];
    const float* patch_b = (const float*)d_in[5];
    const float* Wq      = (const float*)d_in[6];
    const float* bq      = (const float*)d_in[7];
    const float* Wo      = (const float*)d_in[8];
    const float* bo      = (const float*)d_in[9];
    const float* four_wr = (const float*)d_in[10];
    const float* four_wi = (const float*)d_in[11];
    const float* c1      = (const float*)d_in[12];
    const float* c2      = (const float*)d_in[13];
    const float* gamma   = (const float*)d_in[14];
    const float* beta    = (const float*)d_in[15];
    const float* head_W  = (const float*)d_in[16];
    const float* head_b  = (const float*)d_in[17];
    const float* trend_W = (const float*)d_in[18];
    const float* trend_b = (const float*)d_in[19];
    float* out = (float*)d_out;
    float* ws  = (float*)d_ws;

    // workspace layout (floats); total ~31.66M floats ~127 MB
    float* seas  = ws;                       // 1,376,256
    float* trend = ws + 1376256;             // 1,376,256
    float* bufA  = ws + 2752512;             // 4,128,768
    float* bufB  = bufA + 4128768;
    float* bufC  = bufB + 4128768;
    float* big   = bufC + 4128768;           // 16,515,072 (shared: xp / fft bufs / hidden / encT)
    float* xre   = big;
    float* xim   = big + 2031616;
    float* ore   = big + 2*2031616;
    float* oim   = big + 3*2031616;
    float* xp    = big;
    float* hid   = big;
    float* encT  = big;
    float* cosT  = big + 16515072;           // 1953
    float* sinT  = cosT + 1953;              // 1953

    auto cdiv = [](int a, int b) { return (a + b - 1) / b; };

    decomp_input_k<<<cdiv(B_*T_*C_,256),256,0,stream>>>(x_enc, seas, trend);
    trend_head_k<<<cdiv(B_*P_*C_,256),256,0,stream>>>(trend, trend_W, trend_b, head_b, out);
    tables_k<<<cdiv(MODES_*L_,64),64,0,stream>>>(cosT, sinT);
    patches_k<<<cdiv(B_*L_*336,256),256,0,stream>>>(seas, xp);
    gemm_bt<<<dim3(512/64, ML/64),256,0,stream>>>(xp, patch_W, patch_b, bufA, ML, 512, 336, 0);

    for (int l = 0; l < 2; ++l) {
        const float* Wq_l = Wq + (size_t)l*512*512;
        const float* bq_l = bq + (size_t)l*512;
        const float* Wo_l = Wo + (size_t)l*512*512;
        const float* bo_l = bo + (size_t)l*512;
        const float* wr_l = four_wr + (size_t)l*H_*DH_*DH_*MODES_;
        const float* wi_l = four_wi + (size_t)l*H_*DH_*DH_*MODES_;
        const float* c1_l = c1 + (size_t)l*FF_*D_;
        const float* c2_l = c2 + (size_t)l*D_*FF_;

        gemm_bt<<<dim3(8,126),256,0,stream>>>(bufA, Wq_l, bq_l, bufB, ML, 512, 512, 0);
        fftfwd_k<<<cdiv(B_*H_*DH_*MODES_,256),256,0,stream>>>(bufB, cosT, sinT, xre, xim);
        modemix_k<<<H_*MODES_,256,0,stream>>>(xre, xim, wr_l, wi_l, ore, oim);
        ifft_k<<<cdiv(B_*H_*DH_*L_,256),256,0,stream>>>(ore, oim, cosT, sinT, bufC);
        gemm_bt<<<dim3(8,126),256,0,stream>>>(bufC, Wo_l, bo_l, bufB, ML, 512, 512, 0);
        decomp_add_k<<<cdiv(B_*L_*D_,256),256,0,stream>>>(bufA, bufB, bufC);
        gemm_bt<<<dim3(32,126),256,0,stream>>>(bufC, c1_l, nullptr, hid, ML, FF_, 512, 1);
        gemm_bt<<<dim3(8,126),256,0,stream>>>(hid, c2_l, nullptr, bufB, ML, 512, FF_, 0);
        decomp_add_k<<<cdiv(B_*L_*D_,256),256,0,stream>>>(bufC, bufB, bufA);
    }

    layernorm_k<<<ML,64,0,stream>>>(bufA, gamma, beta, bufB);
    colmean_k<<<cdiv(B_*D_,256),256,0,stream>>>(bufB, bufA);
    transp_k<<<cdiv(B_*KHEAD,256),256,0,stream>>>(bufA, encT);
    head_k<<<dim3(NOUT/16, 8),256,0,stream>>>(encT, head_W, out);
}

// Round 2
// 1159.680 us; speedup vs baseline: 2.8894x; 2.8894x over previous
//
#include <hip/hip_runtime.h>
#include <math.h>

#define B_ 128
#define T_ 512
#define C_ 21
#define L_ 63
#define D_ 512
#define H_ 8
#define DH_ 64
#define MODES_ 31
#define FF_ 2048
#define P_ 96
#define KMA 25
#define PAD 12
#define NOUT (P_*C_)      /* 2016 */
#define KHEAD (L_*D_)     /* 32256 */
#define ML (B_*L_)        /* 8064 rows */

typedef __attribute__((ext_vector_type(8))) short short8;
typedef __attribute__((ext_vector_type(4))) float f32x4;

__device__ __forceinline__ unsigned short f2b(float f) {
    union { float f; unsigned u; } v; v.f = f;
    unsigned r = v.u + 0x7FFFu + ((v.u >> 16) & 1u);
    return (unsigned short)(r >> 16);
}

__device__ __forceinline__ void gld_lds16(const void* g, void* l) {
    __builtin_amdgcn_global_load_lds(
        (const __attribute__((address_space(1))) unsigned int*)g,
        (__attribute__((address_space(3))) unsigned int*)l, 16, 0, 0);
}

// ---------------- f32 -> bf16 converter (vectorized), n4 = elems/4 ----------------
__global__ void convw_k(const float* __restrict__ src, unsigned short* __restrict__ dst, int n4) {
    int i = blockIdx.x * 256 + threadIdx.x;
    if (i >= n4) return;
    float4 v = ((const float4*)src)[i];
    uint2 p;
    p.x = (unsigned)f2b(v.x) | ((unsigned)f2b(v.y) << 16);
    p.y = (unsigned)f2b(v.z) | ((unsigned)f2b(v.w) << 16);
    ((uint2*)dst)[i] = p;
}

// ---------------- pad patch_W (512x336 f32) -> (512x384 bf16) ----------------
__global__ void padW_k(const float* __restrict__ w, unsigned short* __restrict__ wb) {
    int idx = blockIdx.x * 256 + threadIdx.x;
    if (idx >= 512*384) return;
    int r = idx / 384, c = idx % 384;
    wb[idx] = (c < 336) ? f2b(w[r*336 + c]) : (unsigned short)0;
}

// ---------------- series_decomp on raw input (T=512) ----------------
__global__ void decomp_input_k(const float* __restrict__ x, float* __restrict__ seas,
                               float* __restrict__ trend) {
    int idx = blockIdx.x * 256 + threadIdx.x;
    if (idx >= B_*T_*C_) return;
    int c = idx % C_; int r = idx / C_; int t = r % T_; int b = r / T_;
    const float* xb = x + (size_t)b * T_ * C_ + c;
    float s = 0.f;
    #pragma unroll
    for (int i = -PAD; i <= PAD; ++i) {
        int tt = t + i; tt = tt < 0 ? 0 : (tt > T_-1 ? T_-1 : tt);
        s += xb[(size_t)tt * C_];
    }
    float mean = s * (1.f / KMA);
    float xv = xb[(size_t)t * C_];
    seas[idx]  = xv - mean;
    trend[idx] = mean;
}

// --------- trend linear head; writes out = trend@W + trend_b + head_b ---------
__global__ void trend_head_k(const float* __restrict__ trend, const float* __restrict__ tW,
                             const float* __restrict__ tb, const float* __restrict__ hb,
                             float* __restrict__ out) {
    int idx = blockIdx.x * 256 + threadIdx.x; // (b,p,c)
    if (idx >= B_*P_*C_) return;
    int c = idx % C_; int r = idx / C_; int p = r % P_; int b = r / P_;
    const float* tr = trend + (size_t)b * T_ * C_ + c;
    const float* w  = tW + (size_t)p * T_;
    float s = 0.f;
    for (int l = 0; l < T_; ++l) s += tr[(size_t)l * C_] * w[l];
    out[idx] = s + tb[p] + hb[p*C_ + c];
}

// ---------------- gather patches -> bf16, zero-padded K 336->384 ----------------
__global__ void patches_k(const float* __restrict__ seas, unsigned short* __restrict__ xpB) {
    int idx = blockIdx.x * 256 + threadIdx.x;
    if (idx >= B_*L_*384) return;
    int col = idx % 384; int r = idx / 384; int n = r % L_; int b = r / L_;
    float v = 0.f;
    if (col < 336) {
        int c = col >> 4; int j = col & 15;
        v = seas[((size_t)b * T_ + 8*n + j) * C_ + c];
    }
    xpB[idx] = f2b(v);
}

// ---------------- DFT tables, arg reduced mod 63 ----------------
__global__ void tables_k(float* __restrict__ cosT, float* __restrict__ sinT) {
    int idx = blockIdx.x * 64 + threadIdx.x;
    if (idx >= MODES_ * L_) return;
    int m = idx / L_, l = idx % L_;
    int r = (m * l) % L_;
    double a = 6.283185307179586476925286766559 * (double)r / 63.0;
    cosT[idx] = (float)cos(a);
    sinT[idx] = (float)sin(a);
}

// ====================== bf16 MFMA GEMM: C = A(MxK) @ W(NxK)^T ======================
// tile 128x128, BK=32, 4 waves (2x2 of 64x64). M%128==0, N%128==0, K%32==0.
// A,W bf16 row-major. Cf (f32) and/or Cb (bf16) outputs; bias f32; act=1 -> exact GELU.
__global__ __launch_bounds__(256) void gemm_mfma(
    const unsigned short* __restrict__ A,
    const unsigned short* __restrict__ W,
    const float* __restrict__ bias,
    float* __restrict__ Cf,
    unsigned short* __restrict__ Cb,
    int M, int N, int K, int act)
{
    __shared__ unsigned short Asl[128*32];
    __shared__ unsigned short Wsl[128*32];
    int bm = blockIdx.y, bn = blockIdx.x;
    int t = threadIdx.x;
    int wave = t >> 6, lane = t & 63;
    int wr = wave >> 1, wc = wave & 1;
    int g2 = lane >> 4;     // k-group 0..3
    int rl = lane & 15;
    f32x4 acc[4][4] = {};

    // staging decode: lane -> (row-in-seg, linear slot)
    int srow = lane >> 2;       // 0..15
    int sslot = lane & 3;

    for (int k0 = 0; k0 < K; k0 += 32) {
        __syncthreads();
        #pragma unroll
        for (int i = 0; i < 2; ++i) {
            int seg = wave*2 + i;
            int rA = seg*16 + srow;                 // 0..127 (covers 32..wave rows? seg 0..7 -> rows 0..127 over both i)
            int koA = 8 * (sslot ^ ((rA >> 1) & 3));
            gld_lds16(A + (size_t)(bm*128 + rA)*K + k0 + koA, &Asl[seg*512]);
            int rW = seg*16 + srow;
            int koW = 8 * (sslot ^ ((rW >> 1) & 3));
            gld_lds16(W + (size_t)(bn*128 + rW)*K + k0 + koW, &Wsl[seg*512]);
        }
        __syncthreads();
        short8 af[4], wf[4];
        #pragma unroll
        for (int m = 0; m < 4; ++m) {
            int r = wr*64 + m*16 + rl;
            af[m] = *(const short8*)&Asl[r*32 + ((g2 ^ ((r>>1)&3)) << 3)];
        }
        #pragma unroll
        for (int n = 0; n < 4; ++n) {
            int r = wc*64 + n*16 + rl;
            wf[n] = *(const short8*)&Wsl[r*32 + ((g2 ^ ((r>>1)&3)) << 3)];
        }
        #pragma unroll
        for (int m = 0; m < 4; ++m)
            #pragma unroll
            for (int n = 0; n < 4; ++n)
                acc[m][n] = __builtin_amdgcn_mfma_f32_16x16x32_bf16(af[m], wf[n], acc[m][n], 0, 0, 0);
    }

    int crow0 = bm*128 + wr*64;
    int ccol0 = bn*128 + wc*64;
    #pragma unroll
    for (int n = 0; n < 4; ++n) {
        int col = ccol0 + n*16 + rl;
        float bv = bias ? bias[col] : 0.f;
        #pragma unroll
        for (int m = 0; m < 4; ++m) {
            #pragma unroll
            for (int j = 0; j < 4; ++j) {
                int row = crow0 + m*16 + g2*4 + j;
                float x = acc[m][n][j] + bv;
                if (act == 1) x = 0.5f * x * (1.f + erff(x * 0.70710678118654752f));
                size_t ix = (size_t)row * N + col;
                if (Cf) Cf[ix] = x;
                if (Cb) Cb[ix] = f2b(x);
            }
        }
    }
}

// ====================== head GEMM: out(128x2016) += enc(128x32256,bf16) @ head_W(2016x32256,f32)^T
// W converted f32->bf16 in-register. tile 128x96, K-chunk 672 (21 steps of 32). grid (21, 48).
__global__ __launch_bounds__(256) void head_mfma(
    const unsigned short* __restrict__ A,
    const float* __restrict__ W,
    float* __restrict__ out)
{
    __shared__ unsigned short Asl[128*32];   // 8KB
    __shared__ unsigned short Wsl[96*32];    // 6KB
    int nt = blockIdx.x;       // 0..20
    int kc = blockIdx.y;       // 0..47
    int t = threadIdx.x;
    int wave = t >> 6, lane = t & 63;
    int wr = wave >> 1, wc = wave & 1;
    int g2 = lane >> 4, rl = lane & 15;
    int srow = lane >> 2, sslot = lane & 3;
    f32x4 acc[4][3] = {};
    int k0base = kc * 672;

    for (int ks = 0; ks < 21; ++ks) {
        int k0 = k0base + ks*32;
        __syncthreads();
        // stage A (128x32) via global_load_lds, pre-swizzled source
        #pragma unroll
        for (int i = 0; i < 2; ++i) {
            int seg = wave*2 + i;
            int rA = seg*16 + srow;
            int koA = 8 * (sslot ^ ((rA >> 1) & 3));
            gld_lds16(A + (size_t)rA * KHEAD + k0 + koA, &Asl[seg*512]);
        }
        // stage W (96x32) f32 -> bf16 reg-staged, swizzled ds_write
        #pragma unroll
        for (int i = 0; i < 3; ++i) {
            int f = t + 256*i;           // 0..767 float4s
            int r = f >> 3, c4 = f & 7;
            float4 w4 = *(const float4*)(W + (size_t)(nt*96 + r) * KHEAD + k0 + c4*4);
            uint2 p;
            p.x = (unsigned)f2b(w4.x) | ((unsigned)f2b(w4.y) << 16);
            p.y = (unsigned)f2b(w4.z) | ((unsigned)f2b(w4.w) << 16);
            *(uint2*)&Wsl[r*32 + (((c4>>1) ^ ((r>>1)&3)) << 3) + ((c4&1) << 2)] = p;
        }
        __syncthreads();
        short8 af[4], wf[3];
        #pragma unroll
        for (int m = 0; m < 4; ++m) {
            int r = wr*64 + m*16 + rl;
            af[m] = *(const short8*)&Asl[r*32 + ((g2 ^ ((r>>1)&3)) << 3)];
        }
        #pragma unroll
        for (int n = 0; n < 3; ++n) {
            int r = wc*48 + n*16 + rl;
            wf[n] = *(const short8*)&Wsl[r*32 + ((g2 ^ ((r>>1)&3)) << 3)];
        }
        #pragma unroll
        for (int m = 0; m < 4; ++m)
            #pragma unroll
            for (int n = 0; n < 3; ++n)
                acc[m][n] = __builtin_amdgcn_mfma_f32_16x16x32_bf16(af[m], wf[n], acc[m][n], 0, 0, 0);
    }

    #pragma unroll
    for (int n = 0; n < 3; ++n) {
        int col = nt*96 + wc*48 + n*16 + rl;
        #pragma unroll
        for (int m = 0; m < 4; ++m) {
            #pragma unroll
            for (int j = 0; j < 4; ++j) {
                int row = wr*64 + m*16 + g2*4 + j;
                atomicAdd(&out[(size_t)row * NOUT + col], acc[m][n][j]);
            }
        }
    }
}

// ---------------- forward DFT of q (per b,h,e,m) ----------------
__global__ void fftfwd_k(const float* __restrict__ q, const float* __restrict__ cosT,
                         const float* __restrict__ sinT,
                         float* __restrict__ xre, float* __restrict__ xim) {
    int idx = blockIdx.x * 256 + threadIdx.x;
    if (idx >= B_*H_*DH_*MODES_) return;
    int m = idx % MODES_; int r = idx / MODES_;
    int e = r % DH_; r /= DH_; int h = r % H_; int b = r / H_;
    const float* qb = q + (size_t)b * L_ * D_ + h * DH_ + e;
    const float* ct = cosT + m * L_;
    const float* st = sinT + m * L_;
    float re = 0.f, im = 0.f;
    for (int l = 0; l < L_; ++l) {
        float v = qb[(size_t)l * D_];
        re += v * ct[l];
        im -= v * st[l];
    }
    xre[idx] = re; xim[idx] = im;
}

// ---------------- complex mode mixing ----------------
__global__ __launch_bounds__(256) void modemix_k(const float* __restrict__ xre,
                                                 const float* __restrict__ xim,
                                                 const float* __restrict__ wr,
                                                 const float* __restrict__ wi,
                                                 float* __restrict__ ore,
                                                 float* __restrict__ oim) {
    __shared__ float wrs[64][64];
    __shared__ float wis[64][64];
    int h = blockIdx.x / MODES_, m = blockIdx.x % MODES_;
    int t = threadIdx.x;
    for (int idx = t; idx < 4096; idx += 256) {
        int e = idx >> 6, f = idx & 63;
        size_t wix = (((size_t)(h*64 + e)) * 64 + f) * MODES_ + m;
        wrs[e][f] = wr[wix]; wis[e][f] = wi[wix];
    }
    __syncthreads();
    int f = t & 63; int bg = t >> 6;
    for (int b = bg; b < B_; b += 4) {
        const float* xr = xre + ((size_t)(b*H_ + h) * DH_) * MODES_ + m;
        const float* xi = xim + ((size_t)(b*H_ + h) * DH_) * MODES_ + m;
        float ar = 0.f, ai = 0.f;
        for (int e = 0; e < 64; ++e) {
            float xrv = xr[(size_t)e * MODES_], xiv = xi[(size_t)e * MODES_];
            ar += xrv * wrs[e][f] - xiv * wis[e][f];
            ai += xrv * wis[e][f] + xiv * wrs[e][f];
        }
        size_t ox = ((size_t)(b*H_ + h) * DH_ + f) * MODES_ + m;
        ore[ox] = ar; oim[ox] = ai;
    }
}

// ---------------- inverse rfft -> bf16 (flat (b,l,d) order) ----------------
__global__ void ifft_k(const float* __restrict__ ore, const float* __restrict__ oim,
                       const float* __restrict__ cosT, const float* __restrict__ sinT,
                       unsigned short* __restrict__ yB) {
    int idx = blockIdx.x * 256 + threadIdx.x;
    if (idx >= B_*H_*DH_*L_) return;
    int l = idx % L_; int r = idx / L_;
    int f = r % DH_; r /= DH_; int h = r % H_; int b = r / H_;
    size_t base = ((size_t)(b*H_ + h) * DH_ + f) * MODES_;
    float s = ore[base];
    for (int m = 1; m < MODES_; ++m)
        s += 2.f * (ore[base+m] * cosT[m*L_ + l] - oim[base+m] * sinT[m*L_ + l]);
    yB[idx] = f2b(s * (1.f / 63.f));
}

// ---------------- (X+Y) - movavg(X+Y), streaming window; dual f32+bf16 out ----------------
__global__ void decomp_add_k(const float* __restrict__ X, const float* __restrict__ Yv,
                             float* __restrict__ outF, unsigned short* __restrict__ outB) {
    int idx = blockIdx.x * 256 + threadIdx.x;  // b*512+d
    if (idx >= B_*D_) return;
    int b = idx >> 9, d = idx & 511;
    const float* xp = X  + (size_t)b * L_ * D_ + d;
    const float* yp = Yv + (size_t)b * L_ * D_ + d;
    float* of = outF + (size_t)b * L_ * D_ + d;
    unsigned short* ob = outB + (size_t)b * L_ * D_ + d;
    #define RD(l) (xp[(size_t)(l) * D_] + yp[(size_t)(l) * D_])
    float sum = 13.f * RD(0);
    #pragma unroll
    for (int j = 1; j <= 12; ++j) sum += RD(j);
    for (int l = 0; l < L_; ++l) {
        float res = RD(l) - sum * (1.f / KMA);
        of[(size_t)l * D_] = res;
        ob[(size_t)l * D_] = f2b(res);
        int add = l + 13 > L_-1 ? L_-1 : l + 13;
        int rem = l - 12 < 0 ? 0 : l - 12;
        sum += RD(add) - RD(rem);
    }
    #undef RD
}

// ---------------- layernorm over last dim (512), one wave per row ----------------
__global__ void layernorm_k(const float* __restrict__ X, const float* __restrict__ g,
                            const float* __restrict__ bt, float* __restrict__ Y) {
    int row = blockIdx.x; int t = threadIdx.x;
    const float* x = X + (size_t)row * D_;
    float v[8]; float s = 0.f, s2 = 0.f;
    #pragma unroll
    for (int i = 0; i < 8; ++i) { v[i] = x[t + 64*i]; s += v[i]; s2 += v[i]*v[i]; }
    #pragma unroll
    for (int o = 32; o > 0; o >>= 1) { s += __shfl_down(s, o); s2 += __shfl_down(s2, o); }
    s = __shfl(s, 0); s2 = __shfl(s2, 0);
    float mu = s * (1.f/D_);
    float var = s2 * (1.f/D_) - mu*mu;
    float rs = rsqrtf(var + 1e-5f);
    #pragma unroll
    for (int i = 0; i < 8; ++i) {
        int d = t + 64*i;
        Y[(size_t)row * D_ + d] = (v[i] - mu) * rs * g[d] + bt[d];
    }
}

// ---------------- subtract mean over L axis, write bf16 ----------------
__global__ void colmean_k(const float* __restrict__ X, unsigned short* __restrict__ outB) {
    int idx = blockIdx.x * 256 + threadIdx.x;
    if (idx >= B_*D_) return;
    int d = idx % D_, b = idx / D_;
    const float* xb = X + (size_t)b * L_ * D_ + d;
    float s = 0.f;
    for (int l = 0; l < L_; ++l) s += xb[(size_t)l * D_];
    s *= (1.f / L_);
    unsigned short* ob = outB + (size_t)b * L_ * D_ + d;
    for (int l = 0; l < L_; ++l) ob[(size_t)l * D_] = f2b(xb[(size_t)l * D_] - s);
}

extern "C" void kernel_launch(void* const* d_in, const int* in_sizes, int n_in,
                              void* d_out, int out_size, void* d_ws, size_t ws_size,
                              hipStream_t stream) {
    const float* x_enc   = (const float*)d_in[0];
    const float* patch_W = (const float*)d_in[4];
    const float* patch_b = (const float*)d_in[5];
    const float* Wq      = (const float*)d_in[6];
    const float* bq      = (const float*)d_in[7];
    const float* Wo      = (const float*)d_in[8];
    const float* bo      = (const float*)d_in[9];
    const float* four_wr = (const float*)d_in[10];
    const float* four_wi = (const float*)d_in[11];
    const float* c1      = (const float*)d_in[12];
    const float* c2      = (const float*)d_in[13];
    const float* gamma   = (const float*)d_in[14];
    const float* beta    = (const float*)d_in[15];
    const float* head_W  = (const float*)d_in[16];
    const float* head_b  = (const float*)d_in[17];
    const float* trend_W = (const float*)d_in[18];
    const float* trend_b = (const float*)d_in[19];
    float* out = (float*)d_out;
    float* ws  = (float*)d_ws;

    // -------- workspace layout (f32 units), ~121 MB --------
    float* seas  = ws;                            // 1,376,256
    float* trend = ws + 1376256;                  // 1,376,256
    float* bufA  = ws + 2752512;                  // 4,128,768
    float* bufB  = ws + 6881280;                  // 4,128,768
    float* bufC  = ws + 11010048;                 // 4,128,768
    unsigned short* bufAb  = (unsigned short*)(ws + 15138816);  // 8064x512 bf16
    unsigned short* tmpB16 = (unsigned short*)(ws + 17203200);  // 8064x512 bf16 (ifft out / decomp1 bf16)
    float* big = ws + 19267584;                   // 8,257,536 f32 union region
    float* xre = big;
    float* xim = big + 2031616;
    float* ore = big + 4063232;
    float* oim = big + 6094848;
    unsigned short* xpB  = (unsigned short*)big;              // 8064x384 bf16 (pre-encoder only)
    unsigned short* hidB = (unsigned short*)big;              // 8064x2048 bf16 (FFN only)
    unsigned short* WqB  = (unsigned short*)(ws + 27525120);  // 2x512x512
    unsigned short* WoB  = (unsigned short*)(ws + 27787264);
    unsigned short* c1B  = (unsigned short*)(ws + 28049408);  // 2x2048x512
    unsigned short* c2B  = (unsigned short*)(ws + 29097984);
    unsigned short* pWB  = (unsigned short*)(ws + 30146560);  // 512x384
    float* cosT = ws + 30244864;                  // 1953 (+pad)
    float* sinT = ws + 30246820;

    auto cdiv = [](int a, int b) { return (a + b - 1) / b; };

    // weight conversions (once per call)
    convw_k<<<cdiv(2*512*512/4,256),256,0,stream>>>(Wq, WqB, 2*512*512/4);
    convw_k<<<cdiv(2*512*512/4,256),256,0,stream>>>(Wo, WoB, 2*512*512/4);
    convw_k<<<cdiv(2*2048*512/4,256),256,0,stream>>>(c1, c1B, 2*2048*512/4);
    convw_k<<<cdiv(2*2048*512/4,256),256,0,stream>>>(c2, c2B, 2*2048*512/4);
    padW_k<<<cdiv(512*384,256),256,0,stream>>>(patch_W, pWB);
    tables_k<<<cdiv(MODES_*L_,64),64,0,stream>>>(cosT, sinT);

    decomp_input_k<<<cdiv(B_*T_*C_,256),256,0,stream>>>(x_enc, seas, trend);
    trend_head_k<<<cdiv(B_*P_*C_,256),256,0,stream>>>(trend, trend_W, trend_b, head_b, out);
    patches_k<<<cdiv(B_*L_*384,256),256,0,stream>>>(seas, xpB);

    // patch embed: (8064x384)@(512x384)^T -> bufA f32 + bufAb bf16
    gemm_mfma<<<dim3(4,63),256,0,stream>>>(xpB, pWB, patch_b, bufA, bufAb, ML, 512, 384, 0);

    for (int l = 0; l < 2; ++l) {
        const unsigned short* WqB_l = WqB + (size_t)l*512*512;
        const unsigned short* WoB_l = WoB + (size_t)l*512*512;
        const unsigned short* c1B_l = c1B + (size_t)l*FF_*D_;
        const unsigned short* c2B_l = c2B + (size_t)l*D_*FF_;
        const float* bq_l = bq + (size_t)l*512;
        const float* bo_l = bo + (size_t)l*512;
        const float* wr_l = four_wr + (size_t)l*H_*DH_*DH_*MODES_;
        const float* wi_l = four_wi + (size_t)l*H_*DH_*DH_*MODES_;

        gemm_mfma<<<dim3(4,63),256,0,stream>>>(bufAb, WqB_l, bq_l, bufB, (unsigned short*)nullptr, ML, 512, 512, 0);
        fftfwd_k<<<cdiv(B_*H_*DH_*MODES_,256),256,0,stream>>>(bufB, cosT, sinT, xre, xim);
        modemix_k<<<H_*MODES_,256,0,stream>>>(xre, xim, wr_l, wi_l, ore, oim);
        ifft_k<<<cdiv(B_*H_*DH_*L_,256),256,0,stream>>>(ore, oim, cosT, sinT, tmpB16);
        gemm_mfma<<<dim3(4,63),256,0,stream>>>(tmpB16, WoB_l, bo_l, bufB, (unsigned short*)nullptr, ML, 512, 512, 0);
        decomp_add_k<<<cdiv(B_*D_,256),256,0,stream>>>(bufA, bufB, bufC, tmpB16);
        gemm_mfma<<<dim3(16,63),256,0,stream>>>(tmpB16, c1B_l, (const float*)nullptr, (float*)nullptr, hidB, ML, FF_, 512, 1);
        gemm_mfma<<<dim3(4,63),256,0,stream>>>(hidB, c2B_l, (const float*)nullptr, bufB, (unsigned short*)nullptr, ML, 512, FF_, 0);
        decomp_add_k<<<cdiv(B_*D_,256),256,0,stream>>>(bufC, bufB, bufA, bufAb);
    }

    layernorm_k<<<ML,64,0,stream>>>(bufA, gamma, beta, bufB);
    colmean_k<<<cdiv(B_*D_,256),256,0,stream>>>(bufB, bufAb);
    head_mfma<<<dim3(21,48),256,0,stream>>>(bufAb, head_W, out);
}

// Round 3
// 713.401 us; speedup vs baseline: 4.6969x; 1.6256x over previous
//
#include <hip/hip_runtime.h>
#include <math.h>

#define B_ 128
#define T_ 512
#define C_ 21
#define L_ 63
#define D_ 512
#define H_ 8
#define DH_ 64
#define MODES_ 31
#define FF_ 2048
#define P_ 96
#define KMA 25
#define PAD 12
#define NOUT (P_*C_)      /* 2016 */
#define KHEAD (L_*D_)     /* 32256 */
#define ML (B_*L_)        /* 8064 rows */

typedef __attribute__((ext_vector_type(8))) short short8;
typedef __attribute__((ext_vector_type(4))) float f32x4;

__device__ __forceinline__ unsigned short f2b(float f) {
    union { float f; unsigned u; } v; v.f = f;
    unsigned r = v.u + 0x7FFFu + ((v.u >> 16) & 1u);
    return (unsigned short)(r >> 16);
}

__device__ __forceinline__ void gld_lds16(const void* g, void* l) {
    __builtin_amdgcn_global_load_lds(
        (const __attribute__((address_space(1))) unsigned int*)g,
        (__attribute__((address_space(3))) unsigned int*)l, 16, 0, 0);
}

// ---------------- f32 -> bf16 converter (vectorized), n4 = elems/4 ----------------
__global__ void convw_k(const float* __restrict__ src, unsigned short* __restrict__ dst, int n4) {
    int i = blockIdx.x * 256 + threadIdx.x;
    if (i >= n4) return;
    float4 v = ((const float4*)src)[i];
    uint2 p;
    p.x = (unsigned)f2b(v.x) | ((unsigned)f2b(v.y) << 16);
    p.y = (unsigned)f2b(v.z) | ((unsigned)f2b(v.w) << 16);
    ((uint2*)dst)[i] = p;
}

// ---------------- pad patch_W (512x336 f32) -> (512x384 bf16) ----------------
__global__ void padW_k(const float* __restrict__ w, unsigned short* __restrict__ wb) {
    int idx = blockIdx.x * 256 + threadIdx.x;
    if (idx >= 512*384) return;
    int r = idx / 384, c = idx % 384;
    wb[idx] = (c < 336) ? f2b(w[r*336 + c]) : (unsigned short)0;
}

// ---------------- series_decomp on raw input (T=512) ----------------
__global__ void decomp_input_k(const float* __restrict__ x, float* __restrict__ seas,
                               float* __restrict__ trend) {
    int idx = blockIdx.x * 256 + threadIdx.x;
    if (idx >= B_*T_*C_) return;
    int c = idx % C_; int r = idx / C_; int t = r % T_; int b = r / T_;
    const float* xb = x + (size_t)b * T_ * C_ + c;
    float s = 0.f;
    #pragma unroll
    for (int i = -PAD; i <= PAD; ++i) {
        int tt = t + i; tt = tt < 0 ? 0 : (tt > T_-1 ? T_-1 : tt);
        s += xb[(size_t)tt * C_];
    }
    float mean = s * (1.f / KMA);
    float xv = xb[(size_t)t * C_];
    seas[idx]  = xv - mean;
    trend[idx] = mean;
}

// --------- trend linear head; writes out = trend@W + trend_b + head_b ---------
__global__ void trend_head_k(const float* __restrict__ trend, const float* __restrict__ tW,
                             const float* __restrict__ tb, const float* __restrict__ hb,
                             float* __restrict__ out) {
    int idx = blockIdx.x * 256 + threadIdx.x; // (b,p,c)
    if (idx >= B_*P_*C_) return;
    int c = idx % C_; int r = idx / C_; int p = r % P_; int b = r / P_;
    const float* tr = trend + (size_t)b * T_ * C_ + c;
    const float* w  = tW + (size_t)p * T_;
    float s = 0.f;
    for (int l = 0; l < T_; ++l) s += tr[(size_t)l * C_] * w[l];
    out[idx] = s + tb[p] + hb[p*C_ + c];
}

// ---------------- gather patches -> bf16, zero-padded K 336->384 ----------------
__global__ void patches_k(const float* __restrict__ seas, unsigned short* __restrict__ xpB) {
    int idx = blockIdx.x * 256 + threadIdx.x;
    if (idx >= B_*L_*384) return;
    int col = idx % 384; int r = idx / 384; int n = r % L_; int b = r / L_;
    float v = 0.f;
    if (col < 336) {
        int c = col >> 4; int j = col & 15;
        v = seas[((size_t)b * T_ + 8*n + j) * C_ + c];
    }
    xpB[idx] = f2b(v);
}

// ---------------- DFT tables (32x63, row 31 zeroed), arg reduced mod 63 ----------------
__global__ void tables_k(float* __restrict__ cosT, float* __restrict__ sinT) {
    int idx = blockIdx.x * 64 + threadIdx.x;
    if (idx >= 32 * L_) return;
    int m = idx / L_, l = idx % L_;
    if (m >= MODES_) { cosT[idx] = 0.f; sinT[idx] = 0.f; return; }
    int r = (m * l) % L_;
    double a = 6.283185307179586476925286766559 * (double)r / 63.0;
    cosT[idx] = (float)cos(a);
    sinT[idx] = (float)sin(a);
}

// ====================== bf16 MFMA GEMM: C = A(MxK) @ W(NxK)^T ======================
// tile 64(M)x128(N), BK=32, 4 waves as 2x2, each wave 32x64. M%64==0, N%128==0, K%32==0.
// Cf (f32) and/or Cb (bf16) outputs; bias f32; act=1 -> exact GELU.
__global__ __launch_bounds__(256) void gemm_mfma(
    const unsigned short* __restrict__ A,
    const unsigned short* __restrict__ W,
    const float* __restrict__ bias,
    float* __restrict__ Cf,
    unsigned short* __restrict__ Cb,
    int M, int N, int K, int act)
{
    __shared__ unsigned short Asl[64*32];
    __shared__ unsigned short Wsl[128*32];
    int bm = blockIdx.y, bn = blockIdx.x;
    int t = threadIdx.x;
    int wave = t >> 6, lane = t & 63;
    int wr = wave >> 1, wc = wave & 1;
    int g2 = lane >> 4;     // k-group 0..3
    int rl = lane & 15;
    f32x4 acc[2][4] = {};
    int srow = lane >> 2;   // 0..15
    int sslot = lane & 3;

    const unsigned short* Ab = A + (size_t)(bm*64) * K;
    const unsigned short* Wb = W + (size_t)(bn*128) * K;

    for (int k0 = 0; k0 < K; k0 += 32) {
        __syncthreads();
        {   // stage A: 4 segs of 16 rows, one per wave
            int rA = wave*16 + srow;
            int koA = 8 * (sslot ^ ((rA >> 1) & 3));
            gld_lds16(Ab + (size_t)rA * K + k0 + koA, &Asl[wave*512]);
        }
        #pragma unroll
        for (int i = 0; i < 2; ++i) {   // stage W: 8 segs
            int seg = wave*2 + i;
            int rW = seg*16 + srow;
            int koW = 8 * (sslot ^ ((rW >> 1) & 3));
            gld_lds16(Wb + (size_t)rW * K + k0 + koW, &Wsl[seg*512]);
        }
        __syncthreads();
        short8 af[2], wf[4];
        #pragma unroll
        for (int m = 0; m < 2; ++m) {
            int r = wr*32 + m*16 + rl;
            af[m] = *(const short8*)&Asl[r*32 + ((g2 ^ ((r>>1)&3)) << 3)];
        }
        #pragma unroll
        for (int n = 0; n < 4; ++n) {
            int r = wc*64 + n*16 + rl;
            wf[n] = *(const short8*)&Wsl[r*32 + ((g2 ^ ((r>>1)&3)) << 3)];
        }
        #pragma unroll
        for (int m = 0; m < 2; ++m)
            #pragma unroll
            for (int n = 0; n < 4; ++n)
                acc[m][n] = __builtin_amdgcn_mfma_f32_16x16x32_bf16(af[m], wf[n], acc[m][n], 0, 0, 0);
    }

    int crow0 = bm*64 + wr*32;
    int ccol0 = bn*128 + wc*64;
    #pragma unroll
    for (int n = 0; n < 4; ++n) {
        int col = ccol0 + n*16 + rl;
        float bv = bias ? bias[col] : 0.f;
        #pragma unroll
        for (int m = 0; m < 2; ++m) {
            #pragma unroll
            for (int j = 0; j < 4; ++j) {
                int row = crow0 + m*16 + g2*4 + j;
                float x = acc[m][n][j] + bv;
                if (act == 1) x = 0.5f * x * (1.f + erff(x * 0.70710678118654752f));
                size_t ix = (size_t)row * N + col;
                if (Cf) Cf[ix] = x;
                if (Cb) Cb[ix] = f2b(x);
            }
        }
    }
}

// ====================== fused Fourier block: DFT -> mode-mix -> iDFT, one block per (b,h) ======================
__global__ __launch_bounds__(256) void fourier_fused_k(
    const float* __restrict__ q,      // (B,63,512) f32
    const float* __restrict__ wr,     // (H,64,64,31) f32
    const float* __restrict__ wi,
    const float* __restrict__ cosT,   // (32,63)
    const float* __restrict__ sinT,
    unsigned short* __restrict__ yB)  // flat (b, h*64+f, l) bf16
{
    __shared__ float q_lds[63][64];
    __shared__ float Xre[64][33];
    __shared__ float Xim[64][33];
    __shared__ float Ore[64][33];
    __shared__ float Oim[64][33];
    int b = blockIdx.x >> 3, h = blockIdx.x & 7;
    int t = threadIdx.x;

    const float* qb = q + ((size_t)b * 63) * 512 + h * 64;
    for (int idx = t; idx < 63*64; idx += 256) {
        int l = idx >> 6, e = idx & 63;
        q_lds[l][e] = qb[(size_t)l * 512 + e];
    }
    __syncthreads();

    // stage 1: X[e][m] = sum_l q[l][e] * exp(-i 2pi m l / 63)
    {
        int e = t & 63, w = t >> 6;
        #pragma unroll
        for (int j = 0; j < 8; ++j) {
            int m = w*8 + j;
            if (m < MODES_) {
                float re = 0.f, im = 0.f;
                for (int l = 0; l < 63; ++l) {
                    float v = q_lds[l][e];
                    re = fmaf(v, cosT[m*63 + l], re);
                    im = fmaf(-v, sinT[m*63 + l], im);
                }
                Xre[e][m] = re; Xim[e][m] = im;
            }
        }
    }
    __syncthreads();

    // stage 2: O[f][m] = sum_e X[e][m] * W[h,e,f,m]  (complex)
    {
        int m = t & 31, g = t >> 5;   // f = g*8 + k
        if (m < MODES_) {
            float o_re[8] = {}, o_im[8] = {};
            const float* wrb = wr + ((size_t)h * 64 * 64) * 31 + (size_t)(g*8) * 31 + m;
            const float* wib = wi + ((size_t)h * 64 * 64) * 31 + (size_t)(g*8) * 31 + m;
            for (int e = 0; e < 64; ++e) {
                float xr = Xre[e][m], xi = Xim[e][m];
                const float* wre = wrb + (size_t)e * 64 * 31;
                const float* wie = wib + (size_t)e * 64 * 31;
                #pragma unroll
                for (int k = 0; k < 8; ++k) {
                    float wrv = wre[(size_t)k * 31];
                    float wiv = wie[(size_t)k * 31];
                    o_re[k] += xr*wrv - xi*wiv;
                    o_im[k] += xr*wiv + xi*wrv;
                }
            }
            #pragma unroll
            for (int k = 0; k < 8; ++k) { Ore[g*8+k][m] = o_re[k]; Oim[g*8+k][m] = o_im[k]; }
        }
    }
    __syncthreads();

    // stage 3: y[f][l] = (1/63)(Ore[f][0] + 2*sum_{m=1..30}(re*cos - im*sin))
    {
        int f = t & 63, w = t >> 6;
        int l0 = w * 16;
        float y[16];
        float r0 = Ore[f][0];
        #pragma unroll
        for (int i = 0; i < 16; ++i) y[i] = r0;
        for (int m = 1; m < MODES_; ++m) {
            float re = 2.f * Ore[f][m], im = 2.f * Oim[f][m];
            #pragma unroll
            for (int i = 0; i < 16; ++i) {
                int l = l0 + i;   // l==63 reads zeroed pad row region; value discarded
                y[i] += re * cosT[m*63 + l] - im * sinT[m*63 + l];
            }
        }
        unsigned short* yo = yB + ((size_t)b * 512 + h*64 + f) * 63 + l0;
        int nl = (w == 3) ? 15 : 16;
        for (int i = 0; i < nl; ++i) yo[i] = f2b(y[i] * (1.f/63.f));
    }
}

// ====================== head GEMM: out(128x2016) += enc(128x32256,bf16) @ head_W(2016x32256,f32)^T
__global__ __launch_bounds__(256) void head_mfma(
    const unsigned short* __restrict__ A,
    const float* __restrict__ W,
    float* __restrict__ out)
{
    __shared__ unsigned short Asl[128*32];
    __shared__ unsigned short Wsl[96*32];
    int nt = blockIdx.x;       // 0..20
    int kc = blockIdx.y;       // 0..47
    int t = threadIdx.x;
    int wave = t >> 6, lane = t & 63;
    int wr = wave >> 1, wc = wave & 1;
    int g2 = lane >> 4, rl = lane & 15;
    int srow = lane >> 2, sslot = lane & 3;
    f32x4 acc[4][3] = {};
    int k0base = kc * 672;

    for (int ks = 0; ks < 21; ++ks) {
        int k0 = k0base + ks*32;
        __syncthreads();
        #pragma unroll
        for (int i = 0; i < 2; ++i) {
            int seg = wave*2 + i;
            int rA = seg*16 + srow;
            int koA = 8 * (sslot ^ ((rA >> 1) & 3));
            gld_lds16(A + (size_t)rA * KHEAD + k0 + koA, &Asl[seg*512]);
        }
        #pragma unroll
        for (int i = 0; i < 3; ++i) {
            int f = t + 256*i;
            int r = f >> 3, c4 = f & 7;
            float4 w4 = *(const float4*)(W + (size_t)(nt*96 + r) * KHEAD + k0 + c4*4);
            uint2 p;
            p.x = (unsigned)f2b(w4.x) | ((unsigned)f2b(w4.y) << 16);
            p.y = (unsigned)f2b(w4.z) | ((unsigned)f2b(w4.w) << 16);
            *(uint2*)&Wsl[r*32 + (((c4>>1) ^ ((r>>1)&3)) << 3) + ((c4&1) << 2)] = p;
        }
        __syncthreads();
        short8 af[4], wf[3];
        #pragma unroll
        for (int m = 0; m < 4; ++m) {
            int r = wr*64 + m*16 + rl;
            af[m] = *(const short8*)&Asl[r*32 + ((g2 ^ ((r>>1)&3)) << 3)];
        }
        #pragma unroll
        for (int n = 0; n < 3; ++n) {
            int r = wc*48 + n*16 + rl;
            wf[n] = *(const short8*)&Wsl[r*32 + ((g2 ^ ((r>>1)&3)) << 3)];
        }
        #pragma unroll
        for (int m = 0; m < 4; ++m)
            #pragma unroll
            for (int n = 0; n < 3; ++n)
                acc[m][n] = __builtin_amdgcn_mfma_f32_16x16x32_bf16(af[m], wf[n], acc[m][n], 0, 0, 0);
    }

    #pragma unroll
    for (int n = 0; n < 3; ++n) {
        int col = nt*96 + wc*48 + n*16 + rl;
        #pragma unroll
        for (int m = 0; m < 4; ++m) {
            #pragma unroll
            for (int j = 0; j < 4; ++j) {
                int row = wr*64 + m*16 + g2*4 + j;
                atomicAdd(&out[(size_t)row * NOUT + col], acc[m][n][j]);
            }
        }
    }
}

// ---------------- (X+Y) - movavg(X+Y), streaming window; dual f32+bf16 out ----------------
__global__ void decomp_add_k(const float* __restrict__ X, const float* __restrict__ Yv,
                             float* __restrict__ outF, unsigned short* __restrict__ outB) {
    int idx = blockIdx.x * 256 + threadIdx.x;  // b*512+d
    if (idx >= B_*D_) return;
    int b = idx >> 9, d = idx & 511;
    const float* xp = X  + (size_t)b * L_ * D_ + d;
    const float* yp = Yv + (size_t)b * L_ * D_ + d;
    float* of = outF + (size_t)b * L_ * D_ + d;
    unsigned short* ob = outB + (size_t)b * L_ * D_ + d;
    #define RD(l) (xp[(size_t)(l) * D_] + yp[(size_t)(l) * D_])
    float sum = 13.f * RD(0);
    #pragma unroll
    for (int j = 1; j <= 12; ++j) sum += RD(j);
    for (int l = 0; l < L_; ++l) {
        float res = RD(l) - sum * (1.f / KMA);
        of[(size_t)l * D_] = res;
        ob[(size_t)l * D_] = f2b(res);
        int add = l + 13 > L_-1 ? L_-1 : l + 13;
        int rem = l - 12 < 0 ? 0 : l - 12;
        sum += RD(add) - RD(rem);
    }
    #undef RD
}

// ---------------- layernorm over last dim (512), one wave per row ----------------
__global__ void layernorm_k(const float* __restrict__ X, const float* __restrict__ g,
                            const float* __restrict__ bt, float* __restrict__ Y) {
    int row = blockIdx.x; int t = threadIdx.x;
    const float* x = X + (size_t)row * D_;
    float v[8]; float s = 0.f, s2 = 0.f;
    #pragma unroll
    for (int i = 0; i < 8; ++i) { v[i] = x[t + 64*i]; s += v[i]; s2 += v[i]*v[i]; }
    #pragma unroll
    for (int o = 32; o > 0; o >>= 1) { s += __shfl_down(s, o); s2 += __shfl_down(s2, o); }
    s = __shfl(s, 0); s2 = __shfl(s2, 0);
    float mu = s * (1.f/D_);
    float var = s2 * (1.f/D_) - mu*mu;
    float rs = rsqrtf(var + 1e-5f);
    #pragma unroll
    for (int i = 0; i < 8; ++i) {
        int d = t + 64*i;
        Y[(size_t)row * D_ + d] = (v[i] - mu) * rs * g[d] + bt[d];
    }
}

// ---------------- subtract mean over L axis, write bf16 ----------------
__global__ void colmean_k(const float* __restrict__ X, unsigned short* __restrict__ outB) {
    int idx = blockIdx.x * 256 + threadIdx.x;
    if (idx >= B_*D_) return;
    int d = idx % D_, b = idx / D_;
    const float* xb = X + (size_t)b * L_ * D_ + d;
    float s = 0.f;
    for (int l = 0; l < L_; ++l) s += xb[(size_t)l * D_];
    s *= (1.f / L_);
    unsigned short* ob = outB + (size_t)b * L_ * D_ + d;
    for (int l = 0; l < L_; ++l) ob[(size_t)l * D_] = f2b(xb[(size_t)l * D_] - s);
}

extern "C" void kernel_launch(void* const* d_in, const int* in_sizes, int n_in,
                              void* d_out, int out_size, void* d_ws, size_t ws_size,
                              hipStream_t stream) {
    const float* x_enc   = (const float*)d_in[0];
    const float* patch_W = (const float*)d_in[4];
    const float* patch_b = (const float*)d_in[5];
    const float* Wq      = (const float*)d_in[6];
    const float* bq      = (const float*)d_in[7];
    const float* Wo      = (const float*)d_in[8];
    const float* bo      = (const float*)d_in[9];
    const float* four_wr = (const float*)d_in[10];
    const float* four_wi = (const float*)d_in[11];
    const float* c1      = (const float*)d_in[12];
    const float* c2      = (const float*)d_in[13];
    const float* gamma   = (const float*)d_in[14];
    const float* beta    = (const float*)d_in[15];
    const float* head_W  = (const float*)d_in[16];
    const float* head_b  = (const float*)d_in[17];
    const float* trend_W = (const float*)d_in[18];
    const float* trend_b = (const float*)d_in[19];
    float* out = (float*)d_out;
    float* ws  = (float*)d_ws;

    float* seas  = ws;                            // 1,376,256
    float* trend = ws + 1376256;                  // 1,376,256
    float* bufA  = ws + 2752512;                  // 4,128,768
    float* bufB  = ws + 6881280;                  // 4,128,768
    float* bufC  = ws + 11010048;                 // 4,128,768
    unsigned short* bufAb  = (unsigned short*)(ws + 15138816);  // 8064x512 bf16
    unsigned short* tmpB16 = (unsigned short*)(ws + 17203200);  // 8064x512 bf16
    float* big = ws + 19267584;                   // union: xpB / hidB
    unsigned short* xpB  = (unsigned short*)big;
    unsigned short* hidB = (unsigned short*)big;
    unsigned short* WqB  = (unsigned short*)(ws + 27525120);
    unsigned short* WoB  = (unsigned short*)(ws + 27787264);
    unsigned short* c1B  = (unsigned short*)(ws + 28049408);
    unsigned short* c2B  = (unsigned short*)(ws + 29097984);
    unsigned short* pWB  = (unsigned short*)(ws + 30146560);
    float* cosT = ws + 30244864;                  // 32*63 = 2016
    float* sinT = ws + 30246880;                  // 32*63

    auto cdiv = [](int a, int b) { return (a + b - 1) / b; };

    convw_k<<<cdiv(2*512*512/4,256),256,0,stream>>>(Wq, WqB, 2*512*512/4);
    convw_k<<<cdiv(2*512*512/4,256),256,0,stream>>>(Wo, WoB, 2*512*512/4);
    convw_k<<<cdiv(2*2048*512/4,256),256,0,stream>>>(c1, c1B, 2*2048*512/4);
    convw_k<<<cdiv(2*2048*512/4,256),256,0,stream>>>(c2, c2B, 2*2048*512/4);
    padW_k<<<cdiv(512*384,256),256,0,stream>>>(patch_W, pWB);
    tables_k<<<cdiv(32*L_,64),64,0,stream>>>(cosT, sinT);

    decomp_input_k<<<cdiv(B_*T_*C_,256),256,0,stream>>>(x_enc, seas, trend);
    trend_head_k<<<cdiv(B_*P_*C_,256),256,0,stream>>>(trend, trend_W, trend_b, head_b, out);
    patches_k<<<cdiv(B_*L_*384,256),256,0,stream>>>(seas, xpB);

    gemm_mfma<<<dim3(4,126),256,0,stream>>>(xpB, pWB, patch_b, bufA, bufAb, ML, 512, 384, 0);

    for (int l = 0; l < 2; ++l) {
        const unsigned short* WqB_l = WqB + (size_t)l*512*512;
        const unsigned short* WoB_l = WoB + (size_t)l*512*512;
        const unsigned short* c1B_l = c1B + (size_t)l*FF_*D_;
        const unsigned short* c2B_l = c2B + (size_t)l*D_*FF_;
        const float* bq_l = bq + (size_t)l*512;
        const float* bo_l = bo + (size_t)l*512;
        const float* wr_l = four_wr + (size_t)l*H_*DH_*DH_*MODES_;
        const float* wi_l = four_wi + (size_t)l*H_*DH_*DH_*MODES_;

        gemm_mfma<<<dim3(4,126),256,0,stream>>>(bufAb, WqB_l, bq_l, bufB, (unsigned short*)nullptr, ML, 512, 512, 0);
        fourier_fused_k<<<B_*H_,256,0,stream>>>(bufB, wr_l, wi_l, cosT, sinT, tmpB16);
        gemm_mfma<<<dim3(4,126),256,0,stream>>>(tmpB16, WoB_l, bo_l, bufB, (unsigned short*)nullptr, ML, 512, 512, 0);
        decomp_add_k<<<cdiv(B_*D_,256),256,0,stream>>>(bufA, bufB, bufC, tmpB16);
        gemm_mfma<<<dim3(16,126),256,0,stream>>>(tmpB16, c1B_l, (const float*)nullptr, (float*)nullptr, hidB, ML, FF_, 512, 1);
        gemm_mfma<<<dim3(4,126),256,0,stream>>>(hidB, c2B_l, (const float*)nullptr, bufB, (unsigned short*)nullptr, ML, 512, FF_, 0);
        decomp_add_k<<<cdiv(B_*D_,256),256,0,stream>>>(bufC, bufB, bufA, bufAb);
    }

    layernorm_k<<<ML,64,0,stream>>>(bufA, gamma, beta, bufB);
    colmean_k<<<cdiv(B_*D_,256),256,0,stream>>>(bufB, bufAb);
    head_mfma<<<dim3(21,48),256,0,stream>>>(bufAb, head_W, out);
}

// Round 4
// 627.417 us; speedup vs baseline: 5.3406x; 1.1370x over previous
//
#include <hip/hip_runtime.h>
#include <math.h>

#define B_ 128
#define T_ 512
#define C_ 21
#define L_ 63
#define D_ 512
#define H_ 8
#define DH_ 64
#define MODES_ 31
#define FF_ 2048
#define P_ 96
#define KMA 25
#define PAD 12
#define NOUT (P_*C_)      /* 2016 */
#define KHEAD (L_*D_)     /* 32256 */
#define ML (B_*L_)        /* 8064 rows */

typedef __attribute__((ext_vector_type(8))) short short8;
typedef __attribute__((ext_vector_type(4))) float f32x4;

__device__ __forceinline__ unsigned short f2b(float f) {
    union { float f; unsigned u; } v; v.f = f;
    unsigned r = v.u + 0x7FFFu + ((v.u >> 16) & 1u);
    return (unsigned short)(r >> 16);
}
__device__ __forceinline__ float b2f(unsigned short u) {
    union { unsigned u; float f; } v; v.u = ((unsigned)u) << 16;
    return v.f;
}
__device__ __forceinline__ void gld_lds16(const void* g, void* l) {
    __builtin_amdgcn_global_load_lds(
        (const __attribute__((address_space(1))) unsigned int*)g,
        (__attribute__((address_space(3))) unsigned int*)l, 16, 0, 0);
}

// ============ prep: all weight conversions + pad + DFT tables, one kernel ============
__global__ void prep_k(const float* __restrict__ Wq, const float* __restrict__ Wo,
                       const float* __restrict__ c1, const float* __restrict__ c2,
                       unsigned short* __restrict__ WqB, unsigned short* __restrict__ WoB,
                       unsigned short* __restrict__ c1B, unsigned short* __restrict__ c2B,
                       const float* __restrict__ pW, unsigned short* __restrict__ pWB,
                       float* __restrict__ cosT, float* __restrict__ sinT) {
    int i = blockIdx.x * 256 + threadIdx.x;
    if (i < 262144) {                       // Wq, Wo (131072 float4 each)
        const float* src = (i < 131072) ? Wq : Wo;
        unsigned short* dst = (i < 131072) ? WqB : WoB;
        int j = i & 131071;
        float4 v = ((const float4*)src)[j];
        uint2 p; p.x = (unsigned)f2b(v.x) | ((unsigned)f2b(v.y) << 16);
        p.y = (unsigned)f2b(v.z) | ((unsigned)f2b(v.w) << 16);
        ((uint2*)dst)[j] = p;
    } else if (i < 1310720) {               // c1, c2 (524288 float4 each)
        int j = i - 262144;
        const float* src = (j < 524288) ? c1 : c2;
        unsigned short* dst = (j < 524288) ? c1B : c2B;
        j &= 524287;
        float4 v = ((const float4*)src)[j];
        uint2 p; p.x = (unsigned)f2b(v.x) | ((unsigned)f2b(v.y) << 16);
        p.y = (unsigned)f2b(v.z) | ((unsigned)f2b(v.w) << 16);
        ((uint2*)dst)[j] = p;
    } else if (i < 1359872) {               // patch_W pad 336->384 (49152 uint2 out)
        int j = i - 1310720;
        int row = j / 96, c4 = j % 96;
        uint2 p; p.x = 0; p.y = 0;
        if (c4 < 84) {
            float4 v = *(const float4*)(pW + (size_t)row * 336 + c4 * 4);
            p.x = (unsigned)f2b(v.x) | ((unsigned)f2b(v.y) << 16);
            p.y = (unsigned)f2b(v.z) | ((unsigned)f2b(v.w) << 16);
        }
        ((uint2*)pWB)[j] = p;
    } else if (i < 1361888) {               // DFT tables (32x63, row 31 zeroed)
        int j = i - 1359872;
        int m = j / 63, l = j % 63;
        if (m >= MODES_) { cosT[j] = 0.f; sinT[j] = 0.f; }
        else {
            int r = (m * l) % 63;
            double a = 6.283185307179586476925286766559 * (double)r / 63.0;
            cosT[j] = (float)cos(a); sinT[j] = (float)sin(a);
        }
    }
}

// ============ series_decomp on input, rolling window, bf16 outputs ============
__global__ void decomp_input_k(const float* __restrict__ x,
                               unsigned short* __restrict__ seasB,
                               unsigned short* __restrict__ trendB) {
    int idx = blockIdx.x * 256 + threadIdx.x;   // (b*21+c)*16 + tc
    if (idx >= B_ * C_ * 16) return;
    int tc = idx & 15; int rc = idx >> 4; int c = rc % C_; int b = rc / C_;
    const float* xb = x + (size_t)b * T_ * C_ + c;
    int t0 = tc * 32;
    float sum = 0.f;
    #pragma unroll
    for (int i = -PAD; i <= PAD; ++i) {
        int tt = t0 + i; tt = tt < 0 ? 0 : (tt > T_-1 ? T_-1 : tt);
        sum += xb[(size_t)tt * C_];
    }
    for (int t = t0; t < t0 + 32; ++t) {
        float mean = sum * (1.f / KMA);
        float xv = xb[(size_t)t * C_];
        size_t o = ((size_t)b * T_ + t) * C_ + c;
        seasB[o]  = f2b(xv - mean);
        trendB[o] = f2b(mean);
        int add = t + 13 > T_-1 ? T_-1 : t + 13;
        int rem = t - 12 < 0 ? 0 : t - 12;
        sum += xb[(size_t)add * C_] - xb[(size_t)rem * C_];
    }
}

// ============ gather patches (bf16 -> bf16, zero-padded K 336->384) ============
__global__ void patches_k(const unsigned short* __restrict__ seasB,
                          unsigned short* __restrict__ xpB) {
    int idx = blockIdx.x * 256 + threadIdx.x;
    if (idx >= B_*L_*384) return;
    int col = idx % 384; int r = idx / 384; int n = r % L_; int b = r / L_;
    unsigned short v = 0;
    if (col < 336) {
        int c = col >> 4; int j = col & 15;
        v = seasB[((size_t)b * T_ + 8*n + j) * C_ + c];
    }
    xpB[idx] = v;
}

// ============ trend head as MFMA GEMM: M=2688 (b,c), N=96 (p), K=512 (t) ============
__global__ __launch_bounds__(256) void trend_mfma(
    const unsigned short* __restrict__ trendB, const float* __restrict__ tW,
    const float* __restrict__ tb, const float* __restrict__ hb,
    float* __restrict__ outT)
{
    __shared__ unsigned short Asl[64*32];
    __shared__ unsigned short Wsl[96*32];
    int bm = blockIdx.x;
    int t = threadIdx.x, wave = t >> 6, lane = t & 63;
    int wr = wave >> 1, wc = wave & 1, g2 = lane >> 4, rl = lane & 15;
    f32x4 acc[2][3] = {};
    int ar = t >> 2, aslot = t & 3;
    int rowg = bm*64 + ar; int ab = rowg / 21, ac = rowg % 21;
    for (int k0 = 0; k0 < 512; k0 += 32) {
        __syncthreads();
        {
            unsigned short vals[8];
            int kb = k0 + aslot*8;
            #pragma unroll
            for (int j = 0; j < 8; ++j)
                vals[j] = trendB[((size_t)ab * T_ + kb + j) * C_ + ac];
            int phys = aslot ^ ((ar>>1)&3);
            *(uint4*)&Asl[ar*32 + phys*8] = *(const uint4*)vals;
        }
        #pragma unroll
        for (int i = 0; i < 3; ++i) {
            int idx = t + 256*i;               // 0..767
            int r = idx >> 3, c4 = idx & 7;
            float4 w4 = *(const float4*)(tW + (size_t)r * T_ + k0 + c4*4);
            uint2 p; p.x = (unsigned)f2b(w4.x) | ((unsigned)f2b(w4.y) << 16);
            p.y = (unsigned)f2b(w4.z) | ((unsigned)f2b(w4.w) << 16);
            *(uint2*)&Wsl[r*32 + (((c4>>1) ^ ((r>>1)&3)) << 3) + ((c4&1) << 2)] = p;
        }
        __syncthreads();
        short8 af[2], wf[3];
        #pragma unroll
        for (int m = 0; m < 2; ++m) {
            int r = wr*32 + m*16 + rl;
            af[m] = *(const short8*)&Asl[r*32 + ((g2 ^ ((r>>1)&3)) << 3)];
        }
        #pragma unroll
        for (int n = 0; n < 3; ++n) {
            int r = wc*48 + n*16 + rl;
            wf[n] = *(const short8*)&Wsl[r*32 + ((g2 ^ ((r>>1)&3)) << 3)];
        }
        #pragma unroll
        for (int m = 0; m < 2; ++m)
            #pragma unroll
            for (int n = 0; n < 3; ++n)
                acc[m][n] = __builtin_amdgcn_mfma_f32_16x16x32_bf16(af[m], wf[n], acc[m][n], 0,0,0);
    }
    #pragma unroll
    for (int n = 0; n < 3; ++n) {
        int p = wc*48 + n*16 + rl;
        float bias = tb[p];
        #pragma unroll
        for (int m = 0; m < 2; ++m)
            #pragma unroll
            for (int j = 0; j < 4; ++j) {
                int rg = bm*64 + wr*32 + m*16 + g2*4 + j;
                int b = rg / 21, c = rg % 21;
                outT[(size_t)b * NOUT + p*21 + c] = acc[m][n][j] + bias + hb[p*21 + c];
            }
    }
}

// ============ bf16 MFMA GEMM, tile 64(M)x128(N), BK=64 ============
__global__ __launch_bounds__(256) void gemm_mfma(
    const unsigned short* __restrict__ A,
    const unsigned short* __restrict__ W,
    const float* __restrict__ bias,
    float* __restrict__ Cf,
    unsigned short* __restrict__ Cb,
    int M, int N, int K, int act)
{
    __shared__ unsigned short Asl[64*64];
    __shared__ unsigned short Wsl[128*64];
    int bm = blockIdx.y, bn = blockIdx.x;
    int t = threadIdx.x;
    int wave = t >> 6, lane = t & 63;
    int wr = wave >> 1, wc = wave & 1;
    int g2 = lane >> 4, rl = lane & 15;
    int lr8 = lane >> 3, l7 = lane & 7;
    f32x4 acc[2][4] = {};
    const unsigned short* Ab = A + (size_t)(bm*64) * K;
    const unsigned short* Wb = W + (size_t)(bn*128) * K;

    for (int k0 = 0; k0 < K; k0 += 64) {
        __syncthreads();
        #pragma unroll
        for (int i = 0; i < 2; ++i) {
            int seg = wave*2 + i;
            int r = seg*8 + lr8;
            int ko = (l7 ^ (r & 7)) << 3;
            gld_lds16(Ab + (size_t)r*K + k0 + ko, &Asl[seg*512]);
        }
        #pragma unroll
        for (int i = 0; i < 4; ++i) {
            int seg = wave*4 + i;
            int r = seg*8 + lr8;
            int ko = (l7 ^ (r & 7)) << 3;
            gld_lds16(Wb + (size_t)r*K + k0 + ko, &Wsl[seg*512]);
        }
        __syncthreads();
        short8 af[2][2], wf[2][4];
        #pragma unroll
        for (int sub = 0; sub < 2; ++sub) {
            #pragma unroll
            for (int m = 0; m < 2; ++m) {
                int r = wr*32 + m*16 + rl;
                af[sub][m] = *(const short8*)&Asl[r*64 + (((sub*4+g2) ^ (r&7)) << 3)];
            }
            #pragma unroll
            for (int n = 0; n < 4; ++n) {
                int r = wc*64 + n*16 + rl;
                wf[sub][n] = *(const short8*)&Wsl[r*64 + (((sub*4+g2) ^ (r&7)) << 3)];
            }
        }
        #pragma unroll
        for (int sub = 0; sub < 2; ++sub)
            #pragma unroll
            for (int m = 0; m < 2; ++m)
                #pragma unroll
                for (int n = 0; n < 4; ++n)
                    acc[m][n] = __builtin_amdgcn_mfma_f32_16x16x32_bf16(af[sub][m], wf[sub][n], acc[m][n], 0,0,0);
    }

    int crow0 = bm*64 + wr*32;
    int ccol0 = bn*128 + wc*64;
    #pragma unroll
    for (int n = 0; n < 4; ++n) {
        int col = ccol0 + n*16 + rl;
        float bv = bias ? bias[col] : 0.f;
        #pragma unroll
        for (int m = 0; m < 2; ++m) {
            #pragma unroll
            for (int j = 0; j < 4; ++j) {
                int row = crow0 + m*16 + g2*4 + j;
                float x = acc[m][n][j] + bv;
                if (act == 1) x = 0.5f * x * (1.f + erff(x * 0.70710678118654752f));
                size_t ix = (size_t)row * N + col;
                if (Cf) Cf[ix] = x;
                if (Cb) Cb[ix] = f2b(x);
            }
        }
    }
}

// ============ fourier stage 1: DFT, block per (b,h) ============
__global__ __launch_bounds__(256) void fourier1_k(
    const float* __restrict__ q, const float* __restrict__ cosT, const float* __restrict__ sinT,
    float* __restrict__ Xre_g, float* __restrict__ Xim_g)
{
    __shared__ float qs[63][64];
    __shared__ float ct[2016], st[2016];
    int b = blockIdx.x >> 3, h = blockIdx.x & 7;
    int t = threadIdx.x;
    for (int idx = t; idx < 1008; idx += 256) {
        int l = idx >> 4, e4 = idx & 15;
        *(float4*)&qs[l][e4*4] = *(const float4*)(q + ((size_t)(b*63 + l))*512 + h*64 + e4*4);
    }
    for (int idx = t; idx < 504; idx += 256) {
        *(float4*)&ct[idx*4] = *(const float4*)(cosT + idx*4);
        *(float4*)&st[idx*4] = *(const float4*)(sinT + idx*4);
    }
    __syncthreads();
    int mm = t & 31, g = t >> 5;
    float re[8] = {}, im[8] = {};
    for (int l = 0; l < 63; ++l) {
        float c = ct[mm*63 + l], s = st[mm*63 + l];
        #pragma unroll
        for (int j = 0; j < 8; ++j) {
            float v = qs[l][g*8 + j];
            re[j] = fmaf(v, c, re[j]);
            im[j] = fmaf(-v, s, im[j]);
        }
    }
    if (mm < MODES_) {
        size_t base = ((size_t)(h*MODES_ + mm)*128 + b)*64 + g*8;
        *(float4*)&Xre_g[base]   = *(float4*)&re[0];
        *(float4*)&Xre_g[base+4] = *(float4*)&re[4];
        *(float4*)&Xim_g[base]   = *(float4*)&im[0];
        *(float4*)&Xim_g[base+4] = *(float4*)&im[4];
    }
}

// ============ fourier stage 2: complex mode-mix via bf16 MFMA, block per (h,m) ============
__global__ __launch_bounds__(256) void fourier2_k(
    const float* __restrict__ Xre_g, const float* __restrict__ Xim_g,
    const float* __restrict__ wr, const float* __restrict__ wi,
    float* __restrict__ Ore_g, float* __restrict__ Oim_g)
{
    __shared__ unsigned short Xr[128*64], Xi[128*64];       // 16KB each
    __shared__ unsigned short Wr[64*64], Wi[64*64], Wn[64*64]; // 8KB each
    int h = blockIdx.x / MODES_, mm = blockIdx.x % MODES_;
    int t = threadIdx.x;
    size_t xbase = ((size_t)(h*MODES_ + mm)) * 128 * 64;
    #pragma unroll
    for (int i = 0; i < 8; ++i) {
        int idx = t + 256*i;                 // 0..2047 float4 tasks
        int r = idx >> 4, c4 = idx & 15;
        int ad = r*64 + (((c4>>1) ^ (r&7)) << 3) + ((c4&1) << 2);
        float4 v = *(const float4*)(Xre_g + xbase + (size_t)r*64 + c4*4);
        uint2 p; p.x = (unsigned)f2b(v.x) | ((unsigned)f2b(v.y) << 16);
        p.y = (unsigned)f2b(v.z) | ((unsigned)f2b(v.w) << 16);
        *(uint2*)&Xr[ad] = p;
        v = *(const float4*)(Xim_g + xbase + (size_t)r*64 + c4*4);
        p.x = (unsigned)f2b(v.x) | ((unsigned)f2b(v.y) << 16);
        p.y = (unsigned)f2b(v.z) | ((unsigned)f2b(v.w) << 16);
        *(uint2*)&Xi[ad] = p;
    }
    #pragma unroll
    for (int i = 0; i < 2; ++i) {
        int idx = t + 256*i;                 // 512 (f,oct) tasks
        int f = idx >> 3, oct = idx & 7;
        unsigned short wrv[8], wiv[8], wnv[8];
        #pragma unroll
        for (int j = 0; j < 8; ++j) {
            int e = oct*8 + j;
            size_t a = (((size_t)(h*64 + e))*64 + f)*MODES_ + mm;
            wrv[j] = f2b(wr[a]);
            wiv[j] = f2b(wi[a]);
            wnv[j] = wiv[j] ^ 0x8000u;
        }
        int ad = f*64 + ((oct ^ (f&7)) << 3);
        *(uint4*)&Wr[ad] = *(const uint4*)wrv;
        *(uint4*)&Wi[ad] = *(const uint4*)wiv;
        *(uint4*)&Wn[ad] = *(const uint4*)wnv;
    }
    __syncthreads();
    int wave = t >> 6, lane = t & 63;
    int wv = wave >> 1, wc = wave & 1;
    int g2 = lane >> 4, rl = lane & 15;
    f32x4 ar[4][2] = {}, ai[4][2] = {};
    #pragma unroll
    for (int sub = 0; sub < 2; ++sub) {
        short8 xr[4], xi[4], br[2], bi[2], bn[2];
        #pragma unroll
        for (int m = 0; m < 4; ++m) {
            int r = wv*64 + m*16 + rl;
            int off = r*64 + (((sub*4+g2) ^ (r&7)) << 3);
            xr[m] = *(const short8*)&Xr[off];
            xi[m] = *(const short8*)&Xi[off];
        }
        #pragma unroll
        for (int n = 0; n < 2; ++n) {
            int r = wc*32 + n*16 + rl;
            int off = r*64 + (((sub*4+g2) ^ (r&7)) << 3);
            br[n] = *(const short8*)&Wr[off];
            bi[n] = *(const short8*)&Wi[off];
            bn[n] = *(const short8*)&Wn[off];
        }
        #pragma unroll
        for (int m = 0; m < 4; ++m)
            #pragma unroll
            for (int n = 0; n < 2; ++n) {
                ar[m][n] = __builtin_amdgcn_mfma_f32_16x16x32_bf16(xr[m], br[n], ar[m][n], 0,0,0);
                ar[m][n] = __builtin_amdgcn_mfma_f32_16x16x32_bf16(xi[m], bn[n], ar[m][n], 0,0,0);
                ai[m][n] = __builtin_amdgcn_mfma_f32_16x16x32_bf16(xr[m], bi[n], ai[m][n], 0,0,0);
                ai[m][n] = __builtin_amdgcn_mfma_f32_16x16x32_bf16(xi[m], br[n], ai[m][n], 0,0,0);
            }
    }
    #pragma unroll
    for (int m = 0; m < 4; ++m)
        #pragma unroll
        for (int n = 0; n < 2; ++n)
            #pragma unroll
            for (int j = 0; j < 4; ++j) {
                int b = wv*64 + m*16 + g2*4 + j;
                int f = wc*32 + n*16 + rl;
                Ore_g[xbase + (size_t)b*64 + f] = ar[m][n][j];
                Oim_g[xbase + (size_t)b*64 + f] = ai[m][n][j];
            }
}

// ============ fourier stage 3: iDFT (drops Im(X0)), block per (b,h), bf16 out ============
__global__ __launch_bounds__(256) void fourier3_k(
    const float* __restrict__ Ore_g, const float* __restrict__ Oim_g,
    const float* __restrict__ cosT, const float* __restrict__ sinT,
    unsigned short* __restrict__ yB)
{
    __shared__ float Ore[31][64], Oim[31][64];
    __shared__ float ct[2016], st[2016];
    int b = blockIdx.x >> 3, h = blockIdx.x & 7;
    int t = threadIdx.x;
    for (int idx = t; idx < 496; idx += 256) {
        int m = idx >> 4, e4 = idx & 15;
        size_t a = ((size_t)(h*MODES_ + m)*128 + b)*64 + e4*4;
        *(float4*)&Ore[m][e4*4] = *(const float4*)(Ore_g + a);
        *(float4*)&Oim[m][e4*4] = *(const float4*)(Oim_g + a);
    }
    for (int idx = t; idx < 504; idx += 256) {
        *(float4*)&ct[idx*4] = *(const float4*)(cosT + idx*4);
        *(float4*)&st[idx*4] = *(const float4*)(sinT + idx*4);
    }
    __syncthreads();
    int f = t & 63, w = t >> 6;
    int l0 = w*16;
    float y[16];
    float r0 = Ore[0][f];
    #pragma unroll
    for (int i = 0; i < 16; ++i) y[i] = r0;
    for (int m = 1; m < MODES_; ++m) {
        float re2 = 2.f*Ore[m][f], im2 = 2.f*Oim[m][f];
        #pragma unroll
        for (int i = 0; i < 16; ++i) {
            y[i] = fmaf(re2, ct[m*63 + l0 + i], y[i]);
            y[i] = fmaf(-im2, st[m*63 + l0 + i], y[i]);
        }
    }
    int nl = (w == 3) ? 15 : 16;
    unsigned short* yo = yB + ((size_t)(b*512) + h*64 + f) * 63 + l0;
    for (int i = 0; i < nl; ++i) yo[i] = f2b(y[i] * (1.f/63.f));
}

// ============ (X+Y) - movavg(X+Y), bf16 in/out, rolling window ============
__global__ void decomp_add_k(const unsigned short* __restrict__ X,
                             const unsigned short* __restrict__ Yv,
                             unsigned short* __restrict__ outB) {
    int idx = blockIdx.x * 256 + threadIdx.x;  // b*512+d
    if (idx >= B_*D_) return;
    int b = idx >> 9, d = idx & 511;
    const unsigned short* xp = X  + (size_t)b * L_ * D_ + d;
    const unsigned short* yp = Yv + (size_t)b * L_ * D_ + d;
    unsigned short* ob = outB + (size_t)b * L_ * D_ + d;
    #define RD(l) (b2f(xp[(size_t)(l) * D_]) + b2f(yp[(size_t)(l) * D_]))
    float sum = 13.f * RD(0);
    #pragma unroll
    for (int j = 1; j <= 12; ++j) sum += RD(j);
    for (int l = 0; l < L_; ++l) {
        float res = RD(l) - sum * (1.f / KMA);
        ob[(size_t)l * D_] = f2b(res);
        int add = l + 13 > L_-1 ? L_-1 : l + 13;
        int rem = l - 12 < 0 ? 0 : l - 12;
        sum += RD(add) - RD(rem);
    }
    #undef RD
}

// ============ fused layernorm (row) + mean-subtract (column over L), block per b ============
__global__ __launch_bounds__(256) void ln_colmean_k(
    const unsigned short* __restrict__ Xb, const float* __restrict__ g,
    const float* __restrict__ bt, unsigned short* __restrict__ outB)
{
    __shared__ unsigned short lds[63][512];   // 63KB bf16
    int b = blockIdx.x;
    int w = threadIdx.x >> 6, lane = threadIdx.x & 63;
    for (int i = 0; i < 16; ++i) {
        int row = w*16 + i;
        if (row >= 63) break;
        const unsigned short* x = Xb + ((size_t)(b*63 + row))*512 + lane*8;
        uint4 raw = *(const uint4*)x;
        const unsigned short* rp = (const unsigned short*)&raw;
        float v[8]; float s = 0.f, s2 = 0.f;
        #pragma unroll
        for (int j = 0; j < 8; ++j) { v[j] = b2f(rp[j]); s += v[j]; s2 += v[j]*v[j]; }
        #pragma unroll
        for (int o = 32; o > 0; o >>= 1) { s += __shfl_down(s, o); s2 += __shfl_down(s2, o); }
        s = __shfl(s, 0); s2 = __shfl(s2, 0);
        float mu = s * (1.f/D_);
        float var = s2 * (1.f/D_) - mu*mu;
        float rs = rsqrtf(var + 1e-5f);
        unsigned short o16[8];
        #pragma unroll
        for (int j = 0; j < 8; ++j) {
            int d = lane*8 + j;
            o16[j] = f2b((v[j] - mu) * rs * g[d] + bt[d]);
        }
        *(uint4*)&lds[row][lane*8] = *(const uint4*)o16;
    }
    __syncthreads();
    #pragma unroll
    for (int i = 0; i < 2; ++i) {
        int d = threadIdx.x + 256*i;
        float s = 0.f;
        for (int l = 0; l < 63; ++l) s += b2f(lds[l][d]);
        s *= (1.f / 63.f);
        for (int l = 0; l < 63; ++l)
            outB[((size_t)(b*63 + l))*512 + d] = f2b(b2f(lds[l][d]) - s);
    }
}

// ============ head GEMM: partial[kc] = enc(128x32256 bf16) @ head_W(2016x32256 f32)^T chunk ============
// grid (42 n-tiles of 48, 12 k-chunks of 2688). W converted f32->bf16 in-register, next-ks prefetch.
__global__ __launch_bounds__(256) void head_mfma(
    const unsigned short* __restrict__ A,
    const float* __restrict__ W,
    float* __restrict__ parts)
{
    __shared__ unsigned short Asl[128*32];    // 8KB
    __shared__ unsigned short Wsl[48*32];     // 3KB
    int nt = blockIdx.x;       // 0..41
    int kc = blockIdx.y;       // 0..11
    int t = threadIdx.x;
    int wave = t >> 6, lane = t & 63;
    int g2 = lane >> 4, rl = lane & 15;
    int srow = lane >> 2, sslot = lane & 3;
    f32x4 acc[2][3] = {};
    int k0base = kc * 2688;
    float4 w4c[2];
    {
        #pragma unroll
        for (int i = 0; i < 2; ++i) {
            int idx = t + 256*i;
            if (idx < 384) {
                int r = idx >> 3, c4 = idx & 7;
                w4c[i] = *(const float4*)(W + (size_t)(nt*48 + r)*KHEAD + k0base + c4*4);
            }
        }
    }
    for (int ks = 0; ks < 84; ++ks) {
        int k0 = k0base + ks*32;
        __syncthreads();
        #pragma unroll
        for (int i = 0; i < 2; ++i) {
            int idx = t + 256*i;
            if (idx < 384) {
                int r = idx >> 3, c4 = idx & 7;
                uint2 p; p.x = (unsigned)f2b(w4c[i].x) | ((unsigned)f2b(w4c[i].y) << 16);
                p.y = (unsigned)f2b(w4c[i].z) | ((unsigned)f2b(w4c[i].w) << 16);
                *(uint2*)&Wsl[r*32 + (((c4>>1) ^ ((r>>1)&3)) << 3) + ((c4&1) << 2)] = p;
            }
        }
        #pragma unroll
        for (int i = 0; i < 2; ++i) {
            int seg = wave*2 + i;
            int rA = seg*16 + srow;
            int koA = (sslot ^ ((rA>>1)&3)) << 3;
            gld_lds16(A + (size_t)rA * KHEAD + k0 + koA, &Asl[seg*512]);
        }
        __syncthreads();
        float4 w4n[2];
        if (ks < 83) {
            int k1 = k0 + 32;
            #pragma unroll
            for (int i = 0; i < 2; ++i) {
                int idx = t + 256*i;
                if (idx < 384) {
                    int r = idx >> 3, c4 = idx & 7;
                    w4n[i] = *(const float4*)(W + (size_t)(nt*48 + r)*KHEAD + k1 + c4*4);
                }
            }
        }
        short8 af[2], wf[3];
        #pragma unroll
        for (int m = 0; m < 2; ++m) {
            int r = wave*32 + m*16 + rl;
            af[m] = *(const short8*)&Asl[r*32 + ((g2 ^ ((r>>1)&3)) << 3)];
        }
        #pragma unroll
        for (int n = 0; n < 3; ++n) {
            int r = n*16 + rl;
            wf[n] = *(const short8*)&Wsl[r*32 + ((g2 ^ ((r>>1)&3)) << 3)];
        }
        #pragma unroll
        for (int m = 0; m < 2; ++m)
            #pragma unroll
            for (int n = 0; n < 3; ++n)
                acc[m][n] = __builtin_amdgcn_mfma_f32_16x16x32_bf16(af[m], wf[n], acc[m][n], 0,0,0);
        if (ks < 83) { w4c[0] = w4n[0]; w4c[1] = w4n[1]; }
    }
    float* pout = parts + (size_t)kc * B_ * NOUT;
    #pragma unroll
    for (int n = 0; n < 3; ++n) {
        int col = nt*48 + n*16 + rl;
        #pragma unroll
        for (int m = 0; m < 2; ++m)
            #pragma unroll
            for (int j = 0; j < 4; ++j) {
                int row = wave*32 + m*16 + g2*4 + j;
                pout[(size_t)row * NOUT + col] = acc[m][n][j];
            }
    }
}

// ============ out = trendout + sum parts ============
__global__ void reduce_k(const float* __restrict__ trendout, const float* __restrict__ parts,
                         float* __restrict__ out) {
    int i = blockIdx.x * 256 + threadIdx.x;   // float4 index
    if (i >= 64512) return;
    float4 s = ((const float4*)trendout)[i];
    for (int kc = 0; kc < 12; ++kc) {
        float4 p = ((const float4*)parts)[(size_t)kc * 64512 + i];
        s.x += p.x; s.y += p.y; s.z += p.z; s.w += p.w;
    }
    ((float4*)out)[i] = s;
}

extern "C" void kernel_launch(void* const* d_in, const int* in_sizes, int n_in,
                              void* d_out, int out_size, void* d_ws, size_t ws_size,
                              hipStream_t stream) {
    const float* x_enc   = (const float*)d_in[0];
    const float* patch_W = (const float*)d_in[4];
    const float* patch_b = (const float*)d_in[5];
    const float* Wq      = (const float*)d_in[6];
    const float* bq      = (const float*)d_in[7];
    const float* Wo      = (const float*)d_in[8];
    const float* bo      = (const float*)d_in[9];
    const float* four_wr = (const float*)d_in[10];
    const float* four_wi = (const float*)d_in[11];
    const float* c1      = (const float*)d_in[12];
    const float* c2      = (const float*)d_in[13];
    const float* gamma   = (const float*)d_in[14];
    const float* beta    = (const float*)d_in[15];
    const float* head_W  = (const float*)d_in[16];
    const float* head_b  = (const float*)d_in[17];
    const float* trend_W = (const float*)d_in[18];
    const float* trend_b = (const float*)d_in[19];
    float* out = (float*)d_out;
    float* ws  = (float*)d_ws;

    // -------- workspace layout (float units), ~118.6MB --------
    unsigned short* seasB  = (unsigned short*)ws;                 // 1376256 u16
    unsigned short* trendB = (unsigned short*)(ws + 688128);      // 1376256 u16
    unsigned short* xpB    = (unsigned short*)(ws + 1376256);     // 8064x384
    unsigned short* bufAb  = (unsigned short*)(ws + 2924544);     // 8064x512
    unsigned short* tmpB16 = (unsigned short*)(ws + 4988928);     // 8064x512 (fourier y / enc)
    unsigned short* tmp2   = (unsigned short*)(ws + 7053312);     // 8064x512 (Wo/c2 out)
    unsigned short* bufCb  = (unsigned short*)(ws + 9117696);     // 8064x512 (decomp1 out)
    float* qF    = ws + 11182080;                                  // 8064x512 f32; also Og re/im
    float* Ore_g = qF;
    float* Oim_g = qF + 2031616;
    float* big   = ws + 15310848;                                  // hidB (8064x2048 bf16) / Xg
    unsigned short* hidB = (unsigned short*)big;
    float* Xre_g = big;
    float* Xim_g = big + 2031616;
    unsigned short* WqB = (unsigned short*)(ws + 23568384);
    unsigned short* WoB = (unsigned short*)(ws + 23830528);
    unsigned short* c1B = (unsigned short*)(ws + 24092672);
    unsigned short* c2B = (unsigned short*)(ws + 25141248);
    unsigned short* pWB = (unsigned short*)(ws + 26189824);
    float* cosT = ws + 26288128;
    float* sinT = ws + 26290144;
    float* trendout = ws + 26292160;                               // 258048
    float* parts = ws + 26550208;                                  // 12*258048

    auto cdiv = [](int a, int b) { return (a + b - 1) / b; };

    prep_k<<<5321,256,0,stream>>>(Wq, Wo, c1, c2, WqB, WoB, c1B, c2B, patch_W, pWB, cosT, sinT);
    decomp_input_k<<<cdiv(B_*C_*16,256),256,0,stream>>>(x_enc, seasB, trendB);
    patches_k<<<cdiv(B_*L_*384,256),256,0,stream>>>(seasB, xpB);
    trend_mfma<<<42,256,0,stream>>>(trendB, trend_W, trend_b, head_b, trendout);

    gemm_mfma<<<dim3(4,126),256,0,stream>>>(xpB, pWB, patch_b, (float*)nullptr, bufAb, ML, 512, 384, 0);

    for (int l = 0; l < 2; ++l) {
        const unsigned short* WqB_l = WqB + (size_t)l*512*512;
        const unsigned short* WoB_l = WoB + (size_t)l*512*512;
        const unsigned short* c1B_l = c1B + (size_t)l*FF_*D_;
        const unsigned short* c2B_l = c2B + (size_t)l*D_*FF_;
        const float* bq_l = bq + (size_t)l*512;
        const float* bo_l = bo + (size_t)l*512;
        const float* wr_l = four_wr + (size_t)l*H_*DH_*DH_*MODES_;
        const float* wi_l = four_wi + (size_t)l*H_*DH_*DH_*MODES_;

        gemm_mfma<<<dim3(4,126),256,0,stream>>>(bufAb, WqB_l, bq_l, qF, (unsigned short*)nullptr, ML, 512, 512, 0);
        fourier1_k<<<B_*H_,256,0,stream>>>(qF, cosT, sinT, Xre_g, Xim_g);
        fourier2_k<<<H_*MODES_,256,0,stream>>>(Xre_g, Xim_g, wr_l, wi_l, Ore_g, Oim_g);
        fourier3_k<<<B_*H_,256,0,stream>>>(Ore_g, Oim_g, cosT, sinT, tmpB16);
        gemm_mfma<<<dim3(4,126),256,0,stream>>>(tmpB16, WoB_l, bo_l, (float*)nullptr, tmp2, ML, 512, 512, 0);
        decomp_add_k<<<cdiv(B_*D_,256),256,0,stream>>>(bufAb, tmp2, bufCb);
        gemm_mfma<<<dim3(16,126),256,0,stream>>>(bufCb, c1B_l, (const float*)nullptr, (float*)nullptr, hidB, ML, FF_, 512, 1);
        gemm_mfma<<<dim3(4,126),256,0,stream>>>(hidB, c2B_l, (const float*)nullptr, (float*)nullptr, tmp2, ML, 512, FF_, 0);
        decomp_add_k<<<cdiv(B_*D_,256),256,0,stream>>>(bufCb, tmp2, bufAb);
    }

    ln_colmean_k<<<B_,256,0,stream>>>(bufAb, gamma, beta, tmpB16);
    head_mfma<<<dim3(42,12),256,0,stream>>>(tmpB16, head_W, parts);
    reduce_k<<<cdiv(64512,256),256,0,stream>>>(trendout, parts, out);
}

// Round 5
// 556.107 us; speedup vs baseline: 6.0254x; 1.1282x over previous
//
#include <hip/hip_runtime.h>
#include <math.h>

#define B_ 128
#define T_ 512
#define C_ 21
#define L_ 63
#define D_ 512
#define H_ 8
#define DH_ 64
#define MODES_ 31
#define FF_ 2048
#define P_ 96
#define KMA 25
#define PAD 12
#define NOUT (P_*C_)      /* 2016 */
#define KHEAD (L_*D_)     /* 32256 */
#define ML (B_*L_)        /* 8064 rows */

typedef __attribute__((ext_vector_type(8))) short short8;
typedef __attribute__((ext_vector_type(4))) float f32x4;

__device__ __forceinline__ unsigned short f2b(float f) {
    union { float f; unsigned u; } v; v.f = f;
    unsigned r = v.u + 0x7FFFu + ((v.u >> 16) & 1u);
    return (unsigned short)(r >> 16);
}
__device__ __forceinline__ float b2f(unsigned short u) {
    union { unsigned u; float f; } v; v.u = ((unsigned)u) << 16;
    return v.f;
}
__device__ __forceinline__ void gld_lds16(const void* g, void* l) {
    __builtin_amdgcn_global_load_lds(
        (const __attribute__((address_space(1))) unsigned int*)g,
        (__attribute__((address_space(3))) unsigned int*)l, 16, 0, 0);
}

// ============ prep: all weight conversions + pad + DFT tables, one kernel ============
__global__ void prep_k(const float* __restrict__ Wq, const float* __restrict__ Wo,
                       const float* __restrict__ c1, const float* __restrict__ c2,
                       unsigned short* __restrict__ WqB, unsigned short* __restrict__ WoB,
                       unsigned short* __restrict__ c1B, unsigned short* __restrict__ c2B,
                       const float* __restrict__ pW, unsigned short* __restrict__ pWB,
                       float* __restrict__ cosT, float* __restrict__ sinT) {
    int i = blockIdx.x * 256 + threadIdx.x;
    if (i < 262144) {
        const float* src = (i < 131072) ? Wq : Wo;
        unsigned short* dst = (i < 131072) ? WqB : WoB;
        int j = i & 131071;
        float4 v = ((const float4*)src)[j];
        uint2 p; p.x = (unsigned)f2b(v.x) | ((unsigned)f2b(v.y) << 16);
        p.y = (unsigned)f2b(v.z) | ((unsigned)f2b(v.w) << 16);
        ((uint2*)dst)[j] = p;
    } else if (i < 1310720) {
        int j = i - 262144;
        const float* src = (j < 524288) ? c1 : c2;
        unsigned short* dst = (j < 524288) ? c1B : c2B;
        j &= 524287;
        float4 v = ((const float4*)src)[j];
        uint2 p; p.x = (unsigned)f2b(v.x) | ((unsigned)f2b(v.y) << 16);
        p.y = (unsigned)f2b(v.z) | ((unsigned)f2b(v.w) << 16);
        ((uint2*)dst)[j] = p;
    } else if (i < 1359872) {
        int j = i - 1310720;
        int row = j / 96, c4 = j % 96;
        uint2 p; p.x = 0; p.y = 0;
        if (c4 < 84) {
            float4 v = *(const float4*)(pW + (size_t)row * 336 + c4 * 4);
            p.x = (unsigned)f2b(v.x) | ((unsigned)f2b(v.y) << 16);
            p.y = (unsigned)f2b(v.z) | ((unsigned)f2b(v.w) << 16);
        }
        ((uint2*)pWB)[j] = p;
    } else if (i < 1361888) {
        int j = i - 1359872;
        int m = j / 63, l = j % 63;
        if (m >= MODES_) { cosT[j] = 0.f; sinT[j] = 0.f; }
        else {
            int r = (m * l) % 63;
            double a = 6.283185307179586476925286766559 * (double)r / 63.0;
            cosT[j] = (float)cos(a); sinT[j] = (float)sin(a);
        }
    }
}

// ============ series_decomp on input, rolling window, bf16 outputs ============
__global__ void decomp_input_k(const float* __restrict__ x,
                               unsigned short* __restrict__ seasB,
                               unsigned short* __restrict__ trendB) {
    int idx = blockIdx.x * 256 + threadIdx.x;
    if (idx >= B_ * C_ * 16) return;
    int tc = idx & 15; int rc = idx >> 4; int c = rc % C_; int b = rc / C_;
    const float* xb = x + (size_t)b * T_ * C_ + c;
    int t0 = tc * 32;
    float sum = 0.f;
    #pragma unroll
    for (int i = -PAD; i <= PAD; ++i) {
        int tt = t0 + i; tt = tt < 0 ? 0 : (tt > T_-1 ? T_-1 : tt);
        sum += xb[(size_t)tt * C_];
    }
    for (int t = t0; t < t0 + 32; ++t) {
        float mean = sum * (1.f / KMA);
        float xv = xb[(size_t)t * C_];
        size_t o = ((size_t)b * T_ + t) * C_ + c;
        seasB[o]  = f2b(xv - mean);
        trendB[o] = f2b(mean);
        int add = t + 13 > T_-1 ? T_-1 : t + 13;
        int rem = t - 12 < 0 ? 0 : t - 12;
        sum += xb[(size_t)add * C_] - xb[(size_t)rem * C_];
    }
}

// ============ gather patches (bf16 -> bf16, zero-padded K 336->384) ============
__global__ void patches_k(const unsigned short* __restrict__ seasB,
                          unsigned short* __restrict__ xpB) {
    int idx = blockIdx.x * 256 + threadIdx.x;
    if (idx >= B_*L_*384) return;
    int col = idx % 384; int r = idx / 384; int n = r % L_; int b = r / L_;
    unsigned short v = 0;
    if (col < 336) {
        int c = col >> 4; int j = col & 15;
        v = seasB[((size_t)b * T_ + 8*n + j) * C_ + c];
    }
    xpB[idx] = v;
}

// ============ trend head as MFMA GEMM: M=2688 (b,c), N=96 (p), K=512 (t) ============
__global__ __launch_bounds__(256) void trend_mfma(
    const unsigned short* __restrict__ trendB, const float* __restrict__ tW,
    const float* __restrict__ tb, const float* __restrict__ hb,
    float* __restrict__ outT)
{
    __shared__ unsigned short Asl[64*32];
    __shared__ unsigned short Wsl[96*32];
    int bm = blockIdx.x;
    int t = threadIdx.x, wave = t >> 6, lane = t & 63;
    int wr = wave >> 1, wc = wave & 1, g2 = lane >> 4, rl = lane & 15;
    f32x4 acc[2][3] = {};
    int ar = t >> 2, aslot = t & 3;
    int rowg = bm*64 + ar; int ab = rowg / 21, ac = rowg % 21;
    for (int k0 = 0; k0 < 512; k0 += 32) {
        __syncthreads();
        {
            unsigned short vals[8];
            int kb = k0 + aslot*8;
            #pragma unroll
            for (int j = 0; j < 8; ++j)
                vals[j] = trendB[((size_t)ab * T_ + kb + j) * C_ + ac];
            int phys = aslot ^ ((ar>>1)&3);
            *(uint4*)&Asl[ar*32 + phys*8] = *(const uint4*)vals;
        }
        #pragma unroll
        for (int i = 0; i < 3; ++i) {
            int idx = t + 256*i;
            int r = idx >> 3, c4 = idx & 7;
            float4 w4 = *(const float4*)(tW + (size_t)r * T_ + k0 + c4*4);
            uint2 p; p.x = (unsigned)f2b(w4.x) | ((unsigned)f2b(w4.y) << 16);
            p.y = (unsigned)f2b(w4.z) | ((unsigned)f2b(w4.w) << 16);
            *(uint2*)&Wsl[r*32 + (((c4>>1) ^ ((r>>1)&3)) << 3) + ((c4&1) << 2)] = p;
        }
        __syncthreads();
        short8 af[2], wf[3];
        #pragma unroll
        for (int m = 0; m < 2; ++m) {
            int r = wr*32 + m*16 + rl;
            af[m] = *(const short8*)&Asl[r*32 + ((g2 ^ ((r>>1)&3)) << 3)];
        }
        #pragma unroll
        for (int n = 0; n < 3; ++n) {
            int r = wc*48 + n*16 + rl;
            wf[n] = *(const short8*)&Wsl[r*32 + ((g2 ^ ((r>>1)&3)) << 3)];
        }
        #pragma unroll
        for (int m = 0; m < 2; ++m)
            #pragma unroll
            for (int n = 0; n < 3; ++n)
                acc[m][n] = __builtin_amdgcn_mfma_f32_16x16x32_bf16(af[m], wf[n], acc[m][n], 0,0,0);
    }
    #pragma unroll
    for (int n = 0; n < 3; ++n) {
        int p = wc*48 + n*16 + rl;
        float bias = tb[p];
        #pragma unroll
        for (int m = 0; m < 2; ++m)
            #pragma unroll
            for (int j = 0; j < 4; ++j) {
                int rg = bm*64 + wr*32 + m*16 + g2*4 + j;
                int b = rg / 21, c = rg % 21;
                outT[(size_t)b * NOUT + p*21 + c] = acc[m][n][j] + bias + hb[p*21 + c];
            }
    }
}

// ============ bf16 MFMA GEMM, tile 64(M)x128(N), BK=64, double-buffered (1 barrier/step) ============
__global__ __launch_bounds__(256) void gemm_mfma(
    const unsigned short* __restrict__ A,
    const unsigned short* __restrict__ W,
    const float* __restrict__ bias,
    float* __restrict__ Cf,
    unsigned short* __restrict__ Cb,
    int M, int N, int K, int act)
{
    __shared__ unsigned short Asl[2][64*64];
    __shared__ unsigned short Wsl[2][128*64];
    int bm = blockIdx.y, bn = blockIdx.x;
    int t = threadIdx.x;
    int wave = t >> 6, lane = t & 63;
    int wr = wave >> 1, wc = wave & 1;
    int g2 = lane >> 4, rl = lane & 15;
    int lr8 = lane >> 3, l7 = lane & 7;
    f32x4 acc[2][4] = {};
    const unsigned short* Ab = A + (size_t)(bm*64) * K;
    const unsigned short* Wb = W + (size_t)(bn*128) * K;

    // prologue: stage k0=0 into buffer 0
    #pragma unroll
    for (int i = 0; i < 2; ++i) {
        int seg = wave*2 + i;
        int r = seg*8 + lr8;
        int ko = (l7 ^ (r & 7)) << 3;
        gld_lds16(Ab + (size_t)r*K + ko, &Asl[0][seg*512]);
    }
    #pragma unroll
    for (int i = 0; i < 4; ++i) {
        int seg = wave*4 + i;
        int r = seg*8 + lr8;
        int ko = (l7 ^ (r & 7)) << 3;
        gld_lds16(Wb + (size_t)r*K + ko, &Wsl[0][seg*512]);
    }

    int cur = 0;
    for (int k0 = 0; k0 < K; k0 += 64, cur ^= 1) {
        __syncthreads();   // drains this wave's outstanding stage + prior reads
        if (k0 + 64 < K) {
            int kn = k0 + 64;
            #pragma unroll
            for (int i = 0; i < 2; ++i) {
                int seg = wave*2 + i;
                int r = seg*8 + lr8;
                int ko = (l7 ^ (r & 7)) << 3;
                gld_lds16(Ab + (size_t)r*K + kn + ko, &Asl[cur^1][seg*512]);
            }
            #pragma unroll
            for (int i = 0; i < 4; ++i) {
                int seg = wave*4 + i;
                int r = seg*8 + lr8;
                int ko = (l7 ^ (r & 7)) << 3;
                gld_lds16(Wb + (size_t)r*K + kn + ko, &Wsl[cur^1][seg*512]);
            }
        }
        short8 af[2][2], wf[2][4];
        #pragma unroll
        for (int sub = 0; sub < 2; ++sub) {
            #pragma unroll
            for (int m = 0; m < 2; ++m) {
                int r = wr*32 + m*16 + rl;
                af[sub][m] = *(const short8*)&Asl[cur][r*64 + (((sub*4+g2) ^ (r&7)) << 3)];
            }
            #pragma unroll
            for (int n = 0; n < 4; ++n) {
                int r = wc*64 + n*16 + rl;
                wf[sub][n] = *(const short8*)&Wsl[cur][r*64 + (((sub*4+g2) ^ (r&7)) << 3)];
            }
        }
        #pragma unroll
        for (int sub = 0; sub < 2; ++sub)
            #pragma unroll
            for (int m = 0; m < 2; ++m)
                #pragma unroll
                for (int n = 0; n < 4; ++n)
                    acc[m][n] = __builtin_amdgcn_mfma_f32_16x16x32_bf16(af[sub][m], wf[sub][n], acc[m][n], 0,0,0);
    }

    int crow0 = bm*64 + wr*32;
    int ccol0 = bn*128 + wc*64;
    #pragma unroll
    for (int n = 0; n < 4; ++n) {
        int col = ccol0 + n*16 + rl;
        float bv = bias ? bias[col] : 0.f;
        #pragma unroll
        for (int m = 0; m < 2; ++m) {
            #pragma unroll
            for (int j = 0; j < 4; ++j) {
                int row = crow0 + m*16 + g2*4 + j;
                float x = acc[m][n][j] + bv;
                if (act == 1) x = 0.5f * x * (1.f + erff(x * 0.70710678118654752f));
                size_t ix = (size_t)row * N + col;
                if (Cf) Cf[ix] = x;
                if (Cb) Cb[ix] = f2b(x);
            }
        }
    }
}

// ============ fourier stage 1: DFT, block per (b,h) ============
__global__ __launch_bounds__(256) void fourier1_k(
    const float* __restrict__ q, const float* __restrict__ cosT, const float* __restrict__ sinT,
    float* __restrict__ Xre_g, float* __restrict__ Xim_g)
{
    __shared__ float qs[63][64];
    __shared__ float ct[2016], st[2016];
    int b = blockIdx.x >> 3, h = blockIdx.x & 7;
    int t = threadIdx.x;
    for (int idx = t; idx < 1008; idx += 256) {
        int l = idx >> 4, e4 = idx & 15;
        *(float4*)&qs[l][e4*4] = *(const float4*)(q + ((size_t)(b*63 + l))*512 + h*64 + e4*4);
    }
    for (int idx = t; idx < 504; idx += 256) {
        *(float4*)&ct[idx*4] = *(const float4*)(cosT + idx*4);
        *(float4*)&st[idx*4] = *(const float4*)(sinT + idx*4);
    }
    __syncthreads();
    int mm = t & 31, g = t >> 5;
    float re[8] = {}, im[8] = {};
    for (int l = 0; l < 63; ++l) {
        float c = ct[mm*63 + l], s = st[mm*63 + l];
        #pragma unroll
        for (int j = 0; j < 8; ++j) {
            float v = qs[l][g*8 + j];
            re[j] = fmaf(v, c, re[j]);
            im[j] = fmaf(-v, s, im[j]);
        }
    }
    if (mm < MODES_) {
        size_t base = ((size_t)(h*MODES_ + mm)*128 + b)*64 + g*8;
        *(float4*)&Xre_g[base]   = *(float4*)&re[0];
        *(float4*)&Xre_g[base+4] = *(float4*)&re[4];
        *(float4*)&Xim_g[base]   = *(float4*)&im[0];
        *(float4*)&Xim_g[base+4] = *(float4*)&im[4];
    }
}

// ============ fourier stage 2: complex mode-mix via bf16 MFMA, block per (h,m) ============
__global__ __launch_bounds__(256) void fourier2_k(
    const float* __restrict__ Xre_g, const float* __restrict__ Xim_g,
    const float* __restrict__ wr, const float* __restrict__ wi,
    float* __restrict__ Ore_g, float* __restrict__ Oim_g)
{
    __shared__ unsigned short Xr[128*64], Xi[128*64];
    __shared__ unsigned short Wr[64*64], Wi[64*64], Wn[64*64];
    int h = blockIdx.x / MODES_, mm = blockIdx.x % MODES_;
    int t = threadIdx.x;
    size_t xbase = ((size_t)(h*MODES_ + mm)) * 128 * 64;
    #pragma unroll
    for (int i = 0; i < 8; ++i) {
        int idx = t + 256*i;
        int r = idx >> 4, c4 = idx & 15;
        int ad = r*64 + (((c4>>1) ^ (r&7)) << 3) + ((c4&1) << 2);
        float4 v = *(const float4*)(Xre_g + xbase + (size_t)r*64 + c4*4);
        uint2 p; p.x = (unsigned)f2b(v.x) | ((unsigned)f2b(v.y) << 16);
        p.y = (unsigned)f2b(v.z) | ((unsigned)f2b(v.w) << 16);
        *(uint2*)&Xr[ad] = p;
        v = *(const float4*)(Xim_g + xbase + (size_t)r*64 + c4*4);
        p.x = (unsigned)f2b(v.x) | ((unsigned)f2b(v.y) << 16);
        p.y = (unsigned)f2b(v.z) | ((unsigned)f2b(v.w) << 16);
        *(uint2*)&Xi[ad] = p;
    }
    #pragma unroll
    for (int i = 0; i < 2; ++i) {
        int idx = t + 256*i;
        int f = idx >> 3, oct = idx & 7;
        unsigned short wrv[8], wiv[8], wnv[8];
        #pragma unroll
        for (int j = 0; j < 8; ++j) {
            int e = oct*8 + j;
            size_t a = (((size_t)(h*64 + e))*64 + f)*MODES_ + mm;
            wrv[j] = f2b(wr[a]);
            wiv[j] = f2b(wi[a]);
            wnv[j] = wiv[j] ^ 0x8000u;
        }
        int ad = f*64 + ((oct ^ (f&7)) << 3);
        *(uint4*)&Wr[ad] = *(const uint4*)wrv;
        *(uint4*)&Wi[ad] = *(const uint4*)wiv;
        *(uint4*)&Wn[ad] = *(const uint4*)wnv;
    }
    __syncthreads();
    int wave = t >> 6, lane = t & 63;
    int wv = wave >> 1, wc = wave & 1;
    int g2 = lane >> 4, rl = lane & 15;
    f32x4 ar[4][2] = {}, ai[4][2] = {};
    #pragma unroll
    for (int sub = 0; sub < 2; ++sub) {
        short8 xr[4], xi[4], br[2], bi[2], bn[2];
        #pragma unroll
        for (int m = 0; m < 4; ++m) {
            int r = wv*64 + m*16 + rl;
            int off = r*64 + (((sub*4+g2) ^ (r&7)) << 3);
            xr[m] = *(const short8*)&Xr[off];
            xi[m] = *(const short8*)&Xi[off];
        }
        #pragma unroll
        for (int n = 0; n < 2; ++n) {
            int r = wc*32 + n*16 + rl;
            int off = r*64 + (((sub*4+g2) ^ (r&7)) << 3);
            br[n] = *(const short8*)&Wr[off];
            bi[n] = *(const short8*)&Wi[off];
            bn[n] = *(const short8*)&Wn[off];
        }
        #pragma unroll
        for (int m = 0; m < 4; ++m)
            #pragma unroll
            for (int n = 0; n < 2; ++n) {
                ar[m][n] = __builtin_amdgcn_mfma_f32_16x16x32_bf16(xr[m], br[n], ar[m][n], 0,0,0);
                ar[m][n] = __builtin_amdgcn_mfma_f32_16x16x32_bf16(xi[m], bn[n], ar[m][n], 0,0,0);
                ai[m][n] = __builtin_amdgcn_mfma_f32_16x16x32_bf16(xr[m], bi[n], ai[m][n], 0,0,0);
                ai[m][n] = __builtin_amdgcn_mfma_f32_16x16x32_bf16(xi[m], br[n], ai[m][n], 0,0,0);
            }
    }
    #pragma unroll
    for (int m = 0; m < 4; ++m)
        #pragma unroll
        for (int n = 0; n < 2; ++n)
            #pragma unroll
            for (int j = 0; j < 4; ++j) {
                int b = wv*64 + m*16 + g2*4 + j;
                int f = wc*32 + n*16 + rl;
                Ore_g[xbase + (size_t)b*64 + f] = ar[m][n][j];
                Oim_g[xbase + (size_t)b*64 + f] = ai[m][n][j];
            }
}

// ============ fourier stage 3: iDFT (drops Im(X0)), block per (b,h), bf16 out ============
__global__ __launch_bounds__(256) void fourier3_k(
    const float* __restrict__ Ore_g, const float* __restrict__ Oim_g,
    const float* __restrict__ cosT, const float* __restrict__ sinT,
    unsigned short* __restrict__ yB)
{
    __shared__ float Ore[31][64], Oim[31][64];
    __shared__ float ct[2016], st[2016];
    int b = blockIdx.x >> 3, h = blockIdx.x & 7;
    int t = threadIdx.x;
    for (int idx = t; idx < 496; idx += 256) {
        int m = idx >> 4, e4 = idx & 15;
        size_t a = ((size_t)(h*MODES_ + m)*128 + b)*64 + e4*4;
        *(float4*)&Ore[m][e4*4] = *(const float4*)(Ore_g + a);
        *(float4*)&Oim[m][e4*4] = *(const float4*)(Oim_g + a);
    }
    for (int idx = t; idx < 504; idx += 256) {
        *(float4*)&ct[idx*4] = *(const float4*)(cosT + idx*4);
        *(float4*)&st[idx*4] = *(const float4*)(sinT + idx*4);
    }
    __syncthreads();
    int f = t & 63, w = t >> 6;
    int l0 = w*16;
    float y[16];
    float r0 = Ore[0][f];
    #pragma unroll
    for (int i = 0; i < 16; ++i) y[i] = r0;
    for (int m = 1; m < MODES_; ++m) {
        float re2 = 2.f*Ore[m][f], im2 = 2.f*Oim[m][f];
        #pragma unroll
        for (int i = 0; i < 16; ++i) {
            y[i] = fmaf(re2, ct[m*63 + l0 + i], y[i]);
            y[i] = fmaf(-im2, st[m*63 + l0 + i], y[i]);
        }
    }
    int nl = (w == 3) ? 15 : 16;
    unsigned short* yo = yB + ((size_t)(b*512) + h*64 + f) * 63 + l0;
    for (int i = 0; i < nl; ++i) yo[i] = f2b(y[i] * (1.f/63.f));
}

// ============ (X+Y) - movavg(X+Y), bf16 in/out, rolling window ============
__global__ void decomp_add_k(const unsigned short* __restrict__ X,
                             const unsigned short* __restrict__ Yv,
                             unsigned short* __restrict__ outB) {
    int idx = blockIdx.x * 256 + threadIdx.x;
    if (idx >= B_*D_) return;
    int b = idx >> 9, d = idx & 511;
    const unsigned short* xp = X  + (size_t)b * L_ * D_ + d;
    const unsigned short* yp = Yv + (size_t)b * L_ * D_ + d;
    unsigned short* ob = outB + (size_t)b * L_ * D_ + d;
    #define RD(l) (b2f(xp[(size_t)(l) * D_]) + b2f(yp[(size_t)(l) * D_]))
    float sum = 13.f * RD(0);
    #pragma unroll
    for (int j = 1; j <= 12; ++j) sum += RD(j);
    for (int l = 0; l < L_; ++l) {
        float res = RD(l) - sum * (1.f / KMA);
        ob[(size_t)l * D_] = f2b(res);
        int add = l + 13 > L_-1 ? L_-1 : l + 13;
        int rem = l - 12 < 0 ? 0 : l - 12;
        sum += RD(add) - RD(rem);
    }
    #undef RD
}

// ============ fused layernorm (row) + mean-subtract (column over L), block per b ============
__global__ __launch_bounds__(256) void ln_colmean_k(
    const unsigned short* __restrict__ Xb, const float* __restrict__ g,
    const float* __restrict__ bt, unsigned short* __restrict__ outB)
{
    __shared__ unsigned short lds[63][512];
    int b = blockIdx.x;
    int w = threadIdx.x >> 6, lane = threadIdx.x & 63;
    for (int i = 0; i < 16; ++i) {
        int row = w*16 + i;
        if (row >= 63) break;
        const unsigned short* x = Xb + ((size_t)(b*63 + row))*512 + lane*8;
        uint4 raw = *(const uint4*)x;
        const unsigned short* rp = (const unsigned short*)&raw;
        float v[8]; float s = 0.f, s2 = 0.f;
        #pragma unroll
        for (int j = 0; j < 8; ++j) { v[j] = b2f(rp[j]); s += v[j]; s2 += v[j]*v[j]; }
        #pragma unroll
        for (int o = 32; o > 0; o >>= 1) { s += __shfl_down(s, o); s2 += __shfl_down(s2, o); }
        s = __shfl(s, 0); s2 = __shfl(s2, 0);
        float mu = s * (1.f/D_);
        float var = s2 * (1.f/D_) - mu*mu;
        float rs = rsqrtf(var + 1e-5f);
        unsigned short o16[8];
        #pragma unroll
        for (int j = 0; j < 8; ++j) {
            int d = lane*8 + j;
            o16[j] = f2b((v[j] - mu) * rs * g[d] + bt[d]);
        }
        *(uint4*)&lds[row][lane*8] = *(const uint4*)o16;
    }
    __syncthreads();
    #pragma unroll
    for (int i = 0; i < 2; ++i) {
        int d = threadIdx.x + 256*i;
        float s = 0.f;
        for (int l = 0; l < 63; ++l) s += b2f(lds[l][d]);
        s *= (1.f / 63.f);
        for (int l = 0; l < 63; ++l)
            outB[((size_t)(b*63 + l))*512 + d] = f2b(b2f(lds[l][d]) - s);
    }
}

// ============ head GEMM v2: barrier-free K-loop, W direct-to-register ============
// grid (42 n-tiles of 48, 12 k-chunks of 2688). 4 waves/block each owning a 672-k slice.
// W: global f32 -> regs -> bf16 (private per wave). A: global bf16 -> regs (L3-hot).
// Wave partials reduced via LDS at end; 12 k-chunk parts summed by reduce_k.
__global__ __launch_bounds__(256) void head_mfma(
    const unsigned short* __restrict__ A,
    const float* __restrict__ W,
    float* __restrict__ parts)
{
    __shared__ float red[128][48];
    int nt = blockIdx.x;       // 0..41
    int kc = blockIdx.y;       // 0..11
    int wv = threadIdx.x >> 6, lane = threadIdx.x & 63;
    int rl = lane & 15, g2 = lane >> 4;
    f32x4 acc[8][3] = {};
    const unsigned short* Ab = A + (size_t)rl * KHEAD;
    const float* Wb = W + (size_t)(nt*48 + rl) * KHEAD;
    int kbeg = kc*2688 + wv*672 + g2*8;

    for (int ks = 0; ks < 21; ++ks) {
        int k = kbeg + ks*32;
        short8 af[8];
        #pragma unroll
        for (int m = 0; m < 8; ++m)
            af[m] = *(const short8*)(Ab + (size_t)(m*16) * KHEAD + k);
        short8 wf[3];
        #pragma unroll
        for (int n = 0; n < 3; ++n) {
            float4 lo = *(const float4*)(Wb + (size_t)(n*16) * KHEAD + k);
            float4 hi = *(const float4*)(Wb + (size_t)(n*16) * KHEAD + k + 4);
            unsigned short u[8] = { f2b(lo.x), f2b(lo.y), f2b(lo.z), f2b(lo.w),
                                    f2b(hi.x), f2b(hi.y), f2b(hi.z), f2b(hi.w) };
            wf[n] = *(const short8*)u;
        }
        #pragma unroll
        for (int m = 0; m < 8; ++m)
            #pragma unroll
            for (int n = 0; n < 3; ++n)
                acc[m][n] = __builtin_amdgcn_mfma_f32_16x16x32_bf16(af[m], wf[n], acc[m][n], 0,0,0);
    }

    // reduce 4 wave-partials via LDS (turn-based)
    for (int w = 0; w < 4; ++w) {
        if (wv == w) {
            #pragma unroll
            for (int m = 0; m < 8; ++m)
                #pragma unroll
                for (int n = 0; n < 3; ++n)
                    #pragma unroll
                    for (int j = 0; j < 4; ++j) {
                        int row = m*16 + g2*4 + j, col = n*16 + rl;
                        if (w == 0) red[row][col] = acc[m][n][j];
                        else        red[row][col] += acc[m][n][j];
                    }
        }
        __syncthreads();
    }
    float* pout = parts + (size_t)kc * (B_*NOUT);
    for (int idx = threadIdx.x; idx < 128*48; idx += 256) {
        int row = idx / 48, col = idx % 48;
        pout[(size_t)row * NOUT + nt*48 + col] = red[row][col];
    }
}

// ============ out = trendout + sum of 12 parts ============
__global__ void reduce_k(const float* __restrict__ trendout, const float* __restrict__ parts,
                         float* __restrict__ out) {
    int i = blockIdx.x * 256 + threadIdx.x;
    if (i >= 64512) return;
    float4 s = ((const float4*)trendout)[i];
    for (int kc = 0; kc < 12; ++kc) {
        float4 p = ((const float4*)parts)[(size_t)kc * 64512 + i];
        s.x += p.x; s.y += p.y; s.z += p.z; s.w += p.w;
    }
    ((float4*)out)[i] = s;
}

extern "C" void kernel_launch(void* const* d_in, const int* in_sizes, int n_in,
                              void* d_out, int out_size, void* d_ws, size_t ws_size,
                              hipStream_t stream) {
    const float* x_enc   = (const float*)d_in[0];
    const float* patch_W = (const float*)d_in[4];
    const float* patch_b = (const float*)d_in[5];
    const float* Wq      = (const float*)d_in[6];
    const float* bq      = (const float*)d_in[7];
    const float* Wo      = (const float*)d_in[8];
    const float* bo      = (const float*)d_in[9];
    const float* four_wr = (const float*)d_in[10];
    const float* four_wi = (const float*)d_in[11];
    const float* c1      = (const float*)d_in[12];
    const float* c2      = (const float*)d_in[13];
    const float* gamma   = (const float*)d_in[14];
    const float* beta    = (const float*)d_in[15];
    const float* head_W  = (const float*)d_in[16];
    const float* head_b  = (const float*)d_in[17];
    const float* trend_W = (const float*)d_in[18];
    const float* trend_b = (const float*)d_in[19];
    float* out = (float*)d_out;
    float* ws  = (float*)d_ws;

    unsigned short* seasB  = (unsigned short*)ws;
    unsigned short* trendB = (unsigned short*)(ws + 688128);
    unsigned short* xpB    = (unsigned short*)(ws + 1376256);
    unsigned short* bufAb  = (unsigned short*)(ws + 2924544);
    unsigned short* tmpB16 = (unsigned short*)(ws + 4988928);
    unsigned short* tmp2   = (unsigned short*)(ws + 7053312);
    unsigned short* bufCb  = (unsigned short*)(ws + 9117696);
    float* qF    = ws + 11182080;
    float* Ore_g = qF;
    float* Oim_g = qF + 2031616;
    float* big   = ws + 15310848;
    unsigned short* hidB = (unsigned short*)big;
    float* Xre_g = big;
    float* Xim_g = big + 2031616;
    unsigned short* WqB = (unsigned short*)(ws + 23568384);
    unsigned short* WoB = (unsigned short*)(ws + 23830528);
    unsigned short* c1B = (unsigned short*)(ws + 24092672);
    unsigned short* c2B = (unsigned short*)(ws + 25141248);
    unsigned short* pWB = (unsigned short*)(ws + 26189824);
    float* cosT = ws + 26288128;
    float* sinT = ws + 26290144;
    float* trendout = ws + 26292160;
    float* parts = ws + 26550208;     // 12 * 258048 floats

    auto cdiv = [](int a, int b) { return (a + b - 1) / b; };

    prep_k<<<5321,256,0,stream>>>(Wq, Wo, c1, c2, WqB, WoB, c1B, c2B, patch_W, pWB, cosT, sinT);
    decomp_input_k<<<cdiv(B_*C_*16,256),256,0,stream>>>(x_enc, seasB, trendB);
    patches_k<<<cdiv(B_*L_*384,256),256,0,stream>>>(seasB, xpB);
    trend_mfma<<<42,256,0,stream>>>(trendB, trend_W, trend_b, head_b, trendout);

    gemm_mfma<<<dim3(4,126),256,0,stream>>>(xpB, pWB, patch_b, (float*)nullptr, bufAb, ML, 512, 384, 0);

    for (int l = 0; l < 2; ++l) {
        const unsigned short* WqB_l = WqB + (size_t)l*512*512;
        const unsigned short* WoB_l = WoB + (size_t)l*512*512;
        const unsigned short* c1B_l = c1B + (size_t)l*FF_*D_;
        const unsigned short* c2B_l = c2B + (size_t)l*D_*FF_;
        const float* bq_l = bq + (size_t)l*512;
        const float* bo_l = bo + (size_t)l*512;
        const float* wr_l = four_wr + (size_t)l*H_*DH_*DH_*MODES_;
        const float* wi_l = four_wi + (size_t)l*H_*DH_*DH_*MODES_;

        gemm_mfma<<<dim3(4,126),256,0,stream>>>(bufAb, WqB_l, bq_l, qF, (unsigned short*)nullptr, ML, 512, 512, 0);
        fourier1_k<<<B_*H_,256,0,stream>>>(qF, cosT, sinT, Xre_g, Xim_g);
        fourier2_k<<<H_*MODES_,256,0,stream>>>(Xre_g, Xim_g, wr_l, wi_l, Ore_g, Oim_g);
        fourier3_k<<<B_*H_,256,0,stream>>>(Ore_g, Oim_g, cosT, sinT, tmpB16);
        gemm_mfma<<<dim3(4,126),256,0,stream>>>(tmpB16, WoB_l, bo_l, (float*)nullptr, tmp2, ML, 512, 512, 0);
        decomp_add_k<<<cdiv(B_*D_,256),256,0,stream>>>(bufAb, tmp2, bufCb);
        gemm_mfma<<<dim3(16,126),256,0,stream>>>(bufCb, c1B_l, (const float*)nullptr, (float*)nullptr, hidB, ML, FF_, 512, 1);
        gemm_mfma<<<dim3(4,126),256,0,stream>>>(hidB, c2B_l, (const float*)nullptr, (float*)nullptr, tmp2, ML, 512, FF_, 0);
        decomp_add_k<<<cdiv(B_*D_,256),256,0,stream>>>(bufCb, tmp2, bufAb);
    }

    ln_colmean_k<<<B_,256,0,stream>>>(bufAb, gamma, beta, tmpB16);
    head_mfma<<<dim3(42,12),256,0,stream>>>(tmpB16, head_W, parts);
    reduce_k<<<cdiv(64512,256),256,0,stream>>>(trendout, parts, out);
}

// Round 6
// 555.982 us; speedup vs baseline: 6.0268x; 1.0002x over previous
//
#include <hip/hip_runtime.h>
#include <math.h>

#define B_ 128
#define T_ 512
#define C_ 21
#define L_ 63
#define D_ 512
#define H_ 8
#define DH_ 64
#define MODES_ 31
#define FF_ 2048
#define P_ 96
#define KMA 25
#define PAD 12
#define NOUT (P_*C_)      /* 2016 */
#define KHEAD (L_*D_)     /* 32256 */
#define ML (B_*L_)        /* 8064 rows */

typedef __attribute__((ext_vector_type(8))) short short8;
typedef __attribute__((ext_vector_type(4))) float f32x4;

__device__ __forceinline__ unsigned short f2b(float f) {
    union { float f; unsigned u; } v; v.f = f;
    unsigned r = v.u + 0x7FFFu + ((v.u >> 16) & 1u);
    return (unsigned short)(r >> 16);
}
__device__ __forceinline__ float b2f(unsigned short u) {
    union { unsigned u; float f; } v; v.u = ((unsigned)u) << 16;
    return v.f;
}
__device__ __forceinline__ void gld_lds16(const void* g, void* l) {
    __builtin_amdgcn_global_load_lds(
        (const __attribute__((address_space(1))) unsigned int*)g,
        (__attribute__((address_space(3))) unsigned int*)l, 16, 0, 0);
}

// ============ prep: all weight conversions + pad + DFT tables, one kernel ============
__global__ void prep_k(const float* __restrict__ Wq, const float* __restrict__ Wo,
                       const float* __restrict__ c1, const float* __restrict__ c2,
                       unsigned short* __restrict__ WqB, unsigned short* __restrict__ WoB,
                       unsigned short* __restrict__ c1B, unsigned short* __restrict__ c2B,
                       const float* __restrict__ pW, unsigned short* __restrict__ pWB,
                       float* __restrict__ cosT, float* __restrict__ sinT) {
    int i = blockIdx.x * 256 + threadIdx.x;
    if (i < 262144) {
        const float* src = (i < 131072) ? Wq : Wo;
        unsigned short* dst = (i < 131072) ? WqB : WoB;
        int j = i & 131071;
        float4 v = ((const float4*)src)[j];
        uint2 p; p.x = (unsigned)f2b(v.x) | ((unsigned)f2b(v.y) << 16);
        p.y = (unsigned)f2b(v.z) | ((unsigned)f2b(v.w) << 16);
        ((uint2*)dst)[j] = p;
    } else if (i < 1310720) {
        int j = i - 262144;
        const float* src = (j < 524288) ? c1 : c2;
        unsigned short* dst = (j < 524288) ? c1B : c2B;
        j &= 524287;
        float4 v = ((const float4*)src)[j];
        uint2 p; p.x = (unsigned)f2b(v.x) | ((unsigned)f2b(v.y) << 16);
        p.y = (unsigned)f2b(v.z) | ((unsigned)f2b(v.w) << 16);
        ((uint2*)dst)[j] = p;
    } else if (i < 1359872) {
        int j = i - 1310720;
        int row = j / 96, c4 = j % 96;
        uint2 p; p.x = 0; p.y = 0;
        if (c4 < 84) {
            float4 v = *(const float4*)(pW + (size_t)row * 336 + c4 * 4);
            p.x = (unsigned)f2b(v.x) | ((unsigned)f2b(v.y) << 16);
            p.y = (unsigned)f2b(v.z) | ((unsigned)f2b(v.w) << 16);
        }
        ((uint2*)pWB)[j] = p;
    } else if (i < 1361888) {
        int j = i - 1359872;
        int m = j / 63, l = j % 63;
        if (m >= MODES_) { cosT[j] = 0.f; sinT[j] = 0.f; }
        else {
            int r = (m * l) % 63;
            double a = 6.283185307179586476925286766559 * (double)r / 63.0;
            cosT[j] = (float)cos(a); sinT[j] = (float)sin(a);
        }
    }
}

// ============ series_decomp on input, rolling window, bf16 outputs ============
__global__ void decomp_input_k(const float* __restrict__ x,
                               unsigned short* __restrict__ seasB,
                               unsigned short* __restrict__ trendB) {
    int idx = blockIdx.x * 256 + threadIdx.x;
    if (idx >= B_ * C_ * 16) return;
    int tc = idx & 15; int rc = idx >> 4; int c = rc % C_; int b = rc / C_;
    const float* xb = x + (size_t)b * T_ * C_ + c;
    int t0 = tc * 32;
    float sum = 0.f;
    #pragma unroll
    for (int i = -PAD; i <= PAD; ++i) {
        int tt = t0 + i; tt = tt < 0 ? 0 : (tt > T_-1 ? T_-1 : tt);
        sum += xb[(size_t)tt * C_];
    }
    for (int t = t0; t < t0 + 32; ++t) {
        float mean = sum * (1.f / KMA);
        float xv = xb[(size_t)t * C_];
        size_t o = ((size_t)b * T_ + t) * C_ + c;
        seasB[o]  = f2b(xv - mean);
        trendB[o] = f2b(mean);
        int add = t + 13 > T_-1 ? T_-1 : t + 13;
        int rem = t - 12 < 0 ? 0 : t - 12;
        sum += xb[(size_t)add * C_] - xb[(size_t)rem * C_];
    }
}

// ============ gather patches (bf16 -> bf16, zero-padded K 336->384) ============
__global__ void patches_k(const unsigned short* __restrict__ seasB,
                          unsigned short* __restrict__ xpB) {
    int idx = blockIdx.x * 256 + threadIdx.x;
    if (idx >= B_*L_*384) return;
    int col = idx % 384; int r = idx / 384; int n = r % L_; int b = r / L_;
    unsigned short v = 0;
    if (col < 336) {
        int c = col >> 4; int j = col & 15;
        v = seasB[((size_t)b * T_ + 8*n + j) * C_ + c];
    }
    xpB[idx] = v;
}

// ============ trend head as MFMA GEMM: M=2688 (b,c), N=96 (p), K=512 (t) ============
__global__ __launch_bounds__(256) void trend_mfma(
    const unsigned short* __restrict__ trendB, const float* __restrict__ tW,
    const float* __restrict__ tb, const float* __restrict__ hb,
    float* __restrict__ outT)
{
    __shared__ unsigned short Asl[64*32];
    __shared__ unsigned short Wsl[96*32];
    int bm = blockIdx.x;
    int t = threadIdx.x, wave = t >> 6, lane = t & 63;
    int wr = wave >> 1, wc = wave & 1, g2 = lane >> 4, rl = lane & 15;
    f32x4 acc[2][3] = {};
    int ar = t >> 2, aslot = t & 3;
    int rowg = bm*64 + ar; int ab = rowg / 21, ac = rowg % 21;
    for (int k0 = 0; k0 < 512; k0 += 32) {
        __syncthreads();
        {
            unsigned short vals[8];
            int kb = k0 + aslot*8;
            #pragma unroll
            for (int j = 0; j < 8; ++j)
                vals[j] = trendB[((size_t)ab * T_ + kb + j) * C_ + ac];
            int phys = aslot ^ ((ar>>1)&3);
            *(uint4*)&Asl[ar*32 + phys*8] = *(const uint4*)vals;
        }
        #pragma unroll
        for (int i = 0; i < 3; ++i) {
            int idx = t + 256*i;
            int r = idx >> 3, c4 = idx & 7;
            float4 w4 = *(const float4*)(tW + (size_t)r * T_ + k0 + c4*4);
            uint2 p; p.x = (unsigned)f2b(w4.x) | ((unsigned)f2b(w4.y) << 16);
            p.y = (unsigned)f2b(w4.z) | ((unsigned)f2b(w4.w) << 16);
            *(uint2*)&Wsl[r*32 + (((c4>>1) ^ ((r>>1)&3)) << 3) + ((c4&1) << 2)] = p;
        }
        __syncthreads();
        short8 af[2], wf[3];
        #pragma unroll
        for (int m = 0; m < 2; ++m) {
            int r = wr*32 + m*16 + rl;
            af[m] = *(const short8*)&Asl[r*32 + ((g2 ^ ((r>>1)&3)) << 3)];
        }
        #pragma unroll
        for (int n = 0; n < 3; ++n) {
            int r = wc*48 + n*16 + rl;
            wf[n] = *(const short8*)&Wsl[r*32 + ((g2 ^ ((r>>1)&3)) << 3)];
        }
        #pragma unroll
        for (int m = 0; m < 2; ++m)
            #pragma unroll
            for (int n = 0; n < 3; ++n)
                acc[m][n] = __builtin_amdgcn_mfma_f32_16x16x32_bf16(af[m], wf[n], acc[m][n], 0,0,0);
    }
    #pragma unroll
    for (int n = 0; n < 3; ++n) {
        int p = wc*48 + n*16 + rl;
        float bias = tb[p];
        #pragma unroll
        for (int m = 0; m < 2; ++m)
            #pragma unroll
            for (int j = 0; j < 4; ++j) {
                int rg = bm*64 + wr*32 + m*16 + g2*4 + j;
                int b = rg / 21, c = rg % 21;
                outT[(size_t)b * NOUT + p*21 + c] = acc[m][n][j] + bias + hb[p*21 + c];
            }
    }
}

// ============ bf16 MFMA GEMM, tile 64(M)x128(N), BK=64, double-buffered (1 barrier/step) ============
__global__ __launch_bounds__(256) void gemm_mfma(
    const unsigned short* __restrict__ A,
    const unsigned short* __restrict__ W,
    const float* __restrict__ bias,
    float* __restrict__ Cf,
    unsigned short* __restrict__ Cb,
    int M, int N, int K, int act)
{
    __shared__ unsigned short Asl[2][64*64];
    __shared__ unsigned short Wsl[2][128*64];
    int bm = blockIdx.y, bn = blockIdx.x;
    int t = threadIdx.x;
    int wave = t >> 6, lane = t & 63;
    int wr = wave >> 1, wc = wave & 1;
    int g2 = lane >> 4, rl = lane & 15;
    int lr8 = lane >> 3, l7 = lane & 7;
    f32x4 acc[2][4] = {};
    const unsigned short* Ab = A + (size_t)(bm*64) * K;
    const unsigned short* Wb = W + (size_t)(bn*128) * K;

    // prologue: stage k0=0 into buffer 0
    #pragma unroll
    for (int i = 0; i < 2; ++i) {
        int seg = wave*2 + i;
        int r = seg*8 + lr8;
        int ko = (l7 ^ (r & 7)) << 3;
        gld_lds16(Ab + (size_t)r*K + ko, &Asl[0][seg*512]);
    }
    #pragma unroll
    for (int i = 0; i < 4; ++i) {
        int seg = wave*4 + i;
        int r = seg*8 + lr8;
        int ko = (l7 ^ (r & 7)) << 3;
        gld_lds16(Wb + (size_t)r*K + ko, &Wsl[0][seg*512]);
    }

    int cur = 0;
    for (int k0 = 0; k0 < K; k0 += 64, cur ^= 1) {
        __syncthreads();   // drains this wave's outstanding stage + prior reads
        if (k0 + 64 < K) {
            int kn = k0 + 64;
            #pragma unroll
            for (int i = 0; i < 2; ++i) {
                int seg = wave*2 + i;
                int r = seg*8 + lr8;
                int ko = (l7 ^ (r & 7)) << 3;
                gld_lds16(Ab + (size_t)r*K + kn + ko, &Asl[cur^1][seg*512]);
            }
            #pragma unroll
            for (int i = 0; i < 4; ++i) {
                int seg = wave*4 + i;
                int r = seg*8 + lr8;
                int ko = (l7 ^ (r & 7)) << 3;
                gld_lds16(Wb + (size_t)r*K + kn + ko, &Wsl[cur^1][seg*512]);
            }
        }
        short8 af[2][2], wf[2][4];
        #pragma unroll
        for (int sub = 0; sub < 2; ++sub) {
            #pragma unroll
            for (int m = 0; m < 2; ++m) {
                int r = wr*32 + m*16 + rl;
                af[sub][m] = *(const short8*)&Asl[cur][r*64 + (((sub*4+g2) ^ (r&7)) << 3)];
            }
            #pragma unroll
            for (int n = 0; n < 4; ++n) {
                int r = wc*64 + n*16 + rl;
                wf[sub][n] = *(const short8*)&Wsl[cur][r*64 + (((sub*4+g2) ^ (r&7)) << 3)];
            }
        }
        #pragma unroll
        for (int sub = 0; sub < 2; ++sub)
            #pragma unroll
            for (int m = 0; m < 2; ++m)
                #pragma unroll
                for (int n = 0; n < 4; ++n)
                    acc[m][n] = __builtin_amdgcn_mfma_f32_16x16x32_bf16(af[sub][m], wf[sub][n], acc[m][n], 0,0,0);
    }

    int crow0 = bm*64 + wr*32;
    int ccol0 = bn*128 + wc*64;
    #pragma unroll
    for (int n = 0; n < 4; ++n) {
        int col = ccol0 + n*16 + rl;
        float bv = bias ? bias[col] : 0.f;
        #pragma unroll
        for (int m = 0; m < 2; ++m) {
            #pragma unroll
            for (int j = 0; j < 4; ++j) {
                int row = crow0 + m*16 + g2*4 + j;
                float x = acc[m][n][j] + bv;
                if (act == 1) x = 0.5f * x * (1.f + erff(x * 0.70710678118654752f));
                size_t ix = (size_t)row * N + col;
                if (Cf) Cf[ix] = x;
                if (Cb) Cb[ix] = f2b(x);
            }
        }
    }
}

// ============ fourier stage 1: DFT, block per (b,h) ============
__global__ __launch_bounds__(256) void fourier1_k(
    const float* __restrict__ q, const float* __restrict__ cosT, const float* __restrict__ sinT,
    float* __restrict__ Xre_g, float* __restrict__ Xim_g)
{
    __shared__ float qs[63][64];
    __shared__ float ct[2016], st[2016];
    int b = blockIdx.x >> 3, h = blockIdx.x & 7;
    int t = threadIdx.x;
    for (int idx = t; idx < 1008; idx += 256) {
        int l = idx >> 4, e4 = idx & 15;
        *(float4*)&qs[l][e4*4] = *(const float4*)(q + ((size_t)(b*63 + l))*512 + h*64 + e4*4);
    }
    for (int idx = t; idx < 504; idx += 256) {
        *(float4*)&ct[idx*4] = *(const float4*)(cosT + idx*4);
        *(float4*)&st[idx*4] = *(const float4*)(sinT + idx*4);
    }
    __syncthreads();
    int mm = t & 31, g = t >> 5;
    float re[8] = {}, im[8] = {};
    for (int l = 0; l < 63; ++l) {
        float c = ct[mm*63 + l], s = st[mm*63 + l];
        #pragma unroll
        for (int j = 0; j < 8; ++j) {
            float v = qs[l][g*8 + j];
            re[j] = fmaf(v, c, re[j]);
            im[j] = fmaf(-v, s, im[j]);
        }
    }
    if (mm < MODES_) {
        size_t base = ((size_t)(h*MODES_ + mm)*128 + b)*64 + g*8;
        *(float4*)&Xre_g[base]   = *(float4*)&re[0];
        *(float4*)&Xre_g[base+4] = *(float4*)&re[4];
        *(float4*)&Xim_g[base]   = *(float4*)&im[0];
        *(float4*)&Xim_g[base+4] = *(float4*)&im[4];
    }
}

// ============ fourier stage 2: complex mode-mix via bf16 MFMA, block per (h,m) ============
__global__ __launch_bounds__(256) void fourier2_k(
    const float* __restrict__ Xre_g, const float* __restrict__ Xim_g,
    const float* __restrict__ wr, const float* __restrict__ wi,
    float* __restrict__ Ore_g, float* __restrict__ Oim_g)
{
    __shared__ unsigned short Xr[128*64], Xi[128*64];
    __shared__ unsigned short Wr[64*64], Wi[64*64], Wn[64*64];
    int h = blockIdx.x / MODES_, mm = blockIdx.x % MODES_;
    int t = threadIdx.x;
    size_t xbase = ((size_t)(h*MODES_ + mm)) * 128 * 64;
    #pragma unroll
    for (int i = 0; i < 8; ++i) {
        int idx = t + 256*i;
        int r = idx >> 4, c4 = idx & 15;
        int ad = r*64 + (((c4>>1) ^ (r&7)) << 3) + ((c4&1) << 2);
        float4 v = *(const float4*)(Xre_g + xbase + (size_t)r*64 + c4*4);
        uint2 p; p.x = (unsigned)f2b(v.x) | ((unsigned)f2b(v.y) << 16);
        p.y = (unsigned)f2b(v.z) | ((unsigned)f2b(v.w) << 16);
        *(uint2*)&Xr[ad] = p;
        v = *(const float4*)(Xim_g + xbase + (size_t)r*64 + c4*4);
        p.x = (unsigned)f2b(v.x) | ((unsigned)f2b(v.y) << 16);
        p.y = (unsigned)f2b(v.z) | ((unsigned)f2b(v.w) << 16);
        *(uint2*)&Xi[ad] = p;
    }
    #pragma unroll
    for (int i = 0; i < 2; ++i) {
        int idx = t + 256*i;
        int f = idx >> 3, oct = idx & 7;
        unsigned short wrv[8], wiv[8], wnv[8];
        #pragma unroll
        for (int j = 0; j < 8; ++j) {
            int e = oct*8 + j;
            size_t a = (((size_t)(h*64 + e))*64 + f)*MODES_ + mm;
            wrv[j] = f2b(wr[a]);
            wiv[j] = f2b(wi[a]);
            wnv[j] = wiv[j] ^ 0x8000u;
        }
        int ad = f*64 + ((oct ^ (f&7)) << 3);
        *(uint4*)&Wr[ad] = *(const uint4*)wrv;
        *(uint4*)&Wi[ad] = *(const uint4*)wiv;
        *(uint4*)&Wn[ad] = *(const uint4*)wnv;
    }
    __syncthreads();
    int wave = t >> 6, lane = t & 63;
    int wv = wave >> 1, wc = wave & 1;
    int g2 = lane >> 4, rl = lane & 15;
    f32x4 ar[4][2] = {}, ai[4][2] = {};
    #pragma unroll
    for (int sub = 0; sub < 2; ++sub) {
        short8 xr[4], xi[4], br[2], bi[2], bn[2];
        #pragma unroll
        for (int m = 0; m < 4; ++m) {
            int r = wv*64 + m*16 + rl;
            int off = r*64 + (((sub*4+g2) ^ (r&7)) << 3);
            xr[m] = *(const short8*)&Xr[off];
            xi[m] = *(const short8*)&Xi[off];
        }
        #pragma unroll
        for (int n = 0; n < 2; ++n) {
            int r = wc*32 + n*16 + rl;
            int off = r*64 + (((sub*4+g2) ^ (r&7)) << 3);
            br[n] = *(const short8*)&Wr[off];
            bi[n] = *(const short8*)&Wi[off];
            bn[n] = *(const short8*)&Wn[off];
        }
        #pragma unroll
        for (int m = 0; m < 4; ++m)
            #pragma unroll
            for (int n = 0; n < 2; ++n) {
                ar[m][n] = __builtin_amdgcn_mfma_f32_16x16x32_bf16(xr[m], br[n], ar[m][n], 0,0,0);
                ar[m][n] = __builtin_amdgcn_mfma_f32_16x16x32_bf16(xi[m], bn[n], ar[m][n], 0,0,0);
                ai[m][n] = __builtin_amdgcn_mfma_f32_16x16x32_bf16(xr[m], bi[n], ai[m][n], 0,0,0);
                ai[m][n] = __builtin_amdgcn_mfma_f32_16x16x32_bf16(xi[m], br[n], ai[m][n], 0,0,0);
            }
    }
    #pragma unroll
    for (int m = 0; m < 4; ++m)
        #pragma unroll
        for (int n = 0; n < 2; ++n)
            #pragma unroll
            for (int j = 0; j < 4; ++j) {
                int b = wv*64 + m*16 + g2*4 + j;
                int f = wc*32 + n*16 + rl;
                Ore_g[xbase + (size_t)b*64 + f] = ar[m][n][j];
                Oim_g[xbase + (size_t)b*64 + f] = ai[m][n][j];
            }
}

// ============ fourier stage 3: iDFT (drops Im(X0)), block per (b,h), bf16 out ============
__global__ __launch_bounds__(256) void fourier3_k(
    const float* __restrict__ Ore_g, const float* __restrict__ Oim_g,
    const float* __restrict__ cosT, const float* __restrict__ sinT,
    unsigned short* __restrict__ yB)
{
    __shared__ float Ore[31][64], Oim[31][64];
    __shared__ float ct[2016], st[2016];
    int b = blockIdx.x >> 3, h = blockIdx.x & 7;
    int t = threadIdx.x;
    for (int idx = t; idx < 496; idx += 256) {
        int m = idx >> 4, e4 = idx & 15;
        size_t a = ((size_t)(h*MODES_ + m)*128 + b)*64 + e4*4;
        *(float4*)&Ore[m][e4*4] = *(const float4*)(Ore_g + a);
        *(float4*)&Oim[m][e4*4] = *(const float4*)(Oim_g + a);
    }
    for (int idx = t; idx < 504; idx += 256) {
        *(float4*)&ct[idx*4] = *(const float4*)(cosT + idx*4);
        *(float4*)&st[idx*4] = *(const float4*)(sinT + idx*4);
    }
    __syncthreads();
    int f = t & 63, w = t >> 6;
    int l0 = w*16;
    float y[16];
    float r0 = Ore[0][f];
    #pragma unroll
    for (int i = 0; i < 16; ++i) y[i] = r0;
    for (int m = 1; m < MODES_; ++m) {
        float re2 = 2.f*Ore[m][f], im2 = 2.f*Oim[m][f];
        #pragma unroll
        for (int i = 0; i < 16; ++i) {
            y[i] = fmaf(re2, ct[m*63 + l0 + i], y[i]);
            y[i] = fmaf(-im2, st[m*63 + l0 + i], y[i]);
        }
    }
    int nl = (w == 3) ? 15 : 16;
    unsigned short* yo = yB + ((size_t)(b*512) + h*64 + f) * 63 + l0;
    for (int i = 0; i < nl; ++i) yo[i] = f2b(y[i] * (1.f/63.f));
}

// ============ (X+Y) - movavg(X+Y), bf16 in/out, rolling window ============
__global__ void decomp_add_k(const unsigned short* __restrict__ X,
                             const unsigned short* __restrict__ Yv,
                             unsigned short* __restrict__ outB) {
    int idx = blockIdx.x * 256 + threadIdx.x;
    if (idx >= B_*D_) return;
    int b = idx >> 9, d = idx & 511;
    const unsigned short* xp = X  + (size_t)b * L_ * D_ + d;
    const unsigned short* yp = Yv + (size_t)b * L_ * D_ + d;
    unsigned short* ob = outB + (size_t)b * L_ * D_ + d;
    #define RD(l) (b2f(xp[(size_t)(l) * D_]) + b2f(yp[(size_t)(l) * D_]))
    float sum = 13.f * RD(0);
    #pragma unroll
    for (int j = 1; j <= 12; ++j) sum += RD(j);
    for (int l = 0; l < L_; ++l) {
        float res = RD(l) - sum * (1.f / KMA);
        ob[(size_t)l * D_] = f2b(res);
        int add = l + 13 > L_-1 ? L_-1 : l + 13;
        int rem = l - 12 < 0 ? 0 : l - 12;
        sum += RD(add) - RD(rem);
    }
    #undef RD
}

// ============ fused layernorm (row) + mean-subtract (column over L), block per b ============
__global__ __launch_bounds__(256) void ln_colmean_k(
    const unsigned short* __restrict__ Xb, const float* __restrict__ g,
    const float* __restrict__ bt, unsigned short* __restrict__ outB)
{
    __shared__ unsigned short lds[63][512];
    int b = blockIdx.x;
    int w = threadIdx.x >> 6, lane = threadIdx.x & 63;
    for (int i = 0; i < 16; ++i) {
        int row = w*16 + i;
        if (row >= 63) break;
        const unsigned short* x = Xb + ((size_t)(b*63 + row))*512 + lane*8;
        uint4 raw = *(const uint4*)x;
        const unsigned short* rp = (const unsigned short*)&raw;
        float v[8]; float s = 0.f, s2 = 0.f;
        #pragma unroll
        for (int j = 0; j < 8; ++j) { v[j] = b2f(rp[j]); s += v[j]; s2 += v[j]*v[j]; }
        #pragma unroll
        for (int o = 32; o > 0; o >>= 1) { s += __shfl_down(s, o); s2 += __shfl_down(s2, o); }
        s = __shfl(s, 0); s2 = __shfl(s2, 0);
        float mu = s * (1.f/D_);
        float var = s2 * (1.f/D_) - mu*mu;
        float rs = rsqrtf(var + 1e-5f);
        unsigned short o16[8];
        #pragma unroll
        for (int j = 0; j < 8; ++j) {
            int d = lane*8 + j;
            o16[j] = f2b((v[j] - mu) * rs * g[d] + bt[d]);
        }
        *(uint4*)&lds[row][lane*8] = *(const uint4*)o16;
    }
    __syncthreads();
    #pragma unroll
    for (int i = 0; i < 2; ++i) {
        int d = threadIdx.x + 256*i;
        float s = 0.f;
        for (int l = 0; l < 63; ++l) s += b2f(lds[l][d]);
        s *= (1.f / 63.f);
        for (int l = 0; l < 63; ++l)
            outB[((size_t)(b*63 + l))*512 + d] = f2b(b2f(lds[l][d]) - s);
    }
}

// ============ head GEMM v2: barrier-free K-loop, W direct-to-register ============
// grid (42 n-tiles of 48, 12 k-chunks of 2688). 4 waves/block each owning a 672-k slice.
// W: global f32 -> regs -> bf16 (private per wave). A: global bf16 -> regs (L3-hot).
// Wave partials reduced via LDS at end; 12 k-chunk parts summed by reduce_k.
__global__ __launch_bounds__(256) void head_mfma(
    const unsigned short* __restrict__ A,
    const float* __restrict__ W,
    float* __restrict__ parts)
{
    __shared__ float red[128][48];
    int nt = blockIdx.x;       // 0..41
    int kc = blockIdx.y;       // 0..11
    int wv = threadIdx.x >> 6, lane = threadIdx.x & 63;
    int rl = lane & 15, g2 = lane >> 4;
    f32x4 acc[8][3] = {};
    const unsigned short* Ab = A + (size_t)rl * KHEAD;
    const float* Wb = W + (size_t)(nt*48 + rl) * KHEAD;
    int kbeg = kc*2688 + wv*672 + g2*8;

    for (int ks = 0; ks < 21; ++ks) {
        int k = kbeg + ks*32;
        short8 af[8];
        #pragma unroll
        for (int m = 0; m < 8; ++m)
            af[m] = *(const short8*)(Ab + (size_t)(m*16) * KHEAD + k);
        short8 wf[3];
        #pragma unroll
        for (int n = 0; n < 3; ++n) {
            float4 lo = *(const float4*)(Wb + (size_t)(n*16) * KHEAD + k);
            float4 hi = *(const float4*)(Wb + (size_t)(n*16) * KHEAD + k + 4);
            unsigned short u[8] = { f2b(lo.x), f2b(lo.y), f2b(lo.z), f2b(lo.w),
                                    f2b(hi.x), f2b(hi.y), f2b(hi.z), f2b(hi.w) };
            wf[n] = *(const short8*)u;
        }
        #pragma unroll
        for (int m = 0; m < 8; ++m)
            #pragma unroll
            for (int n = 0; n < 3; ++n)
                acc[m][n] = __builtin_amdgcn_mfma_f32_16x16x32_bf16(af[m], wf[n], acc[m][n], 0,0,0);
    }

    // reduce 4 wave-partials via LDS (turn-based)
    for (int w = 0; w < 4; ++w) {
        if (wv == w) {
            #pragma unroll
            for (int m = 0; m < 8; ++m)
                #pragma unroll
                for (int n = 0; n < 3; ++n)
                    #pragma unroll
                    for (int j = 0; j < 4; ++j) {
                        int row = m*16 + g2*4 + j, col = n*16 + rl;
                        if (w == 0) red[row][col] = acc[m][n][j];
                        else        red[row][col] += acc[m][n][j];
                    }
        }
        __syncthreads();
    }
    float* pout = parts + (size_t)kc * (B_*NOUT);
    for (int idx = threadIdx.x; idx < 128*48; idx += 256) {
        int row = idx / 48, col = idx % 48;
        pout[(size_t)row * NOUT + nt*48 + col] = red[row][col];
    }
}

// ============ out = trendout + sum of 12 parts ============
__global__ void reduce_k(const float* __restrict__ trendout, const float* __restrict__ parts,
                         float* __restrict__ out) {
    int i = blockIdx.x * 256 + threadIdx.x;
    if (i >= 64512) return;
    float4 s = ((const float4*)trendout)[i];
    for (int kc = 0; kc < 12; ++kc) {
        float4 p = ((const float4*)parts)[(size_t)kc * 64512 + i];
        s.x += p.x; s.y += p.y; s.z += p.z; s.w += p.w;
    }
    ((float4*)out)[i] = s;
}

extern "C" void kernel_launch(void* const* d_in, const int* in_sizes, int n_in,
                              void* d_out, int out_size, void* d_ws, size_t ws_size,
                              hipStream_t stream) {
    const float* x_enc   = (const float*)d_in[0];
    const float* patch_W = (const float*)d_in[4];
    const float* patch_b = (const float*)d_in[5];
    const float* Wq      = (const float*)d_in[6];
    const float* bq      = (const float*)d_in[7];
    const float* Wo      = (const float*)d_in[8];
    const float* bo      = (const float*)d_in[9];
    const float* four_wr = (const float*)d_in[10];
    const float* four_wi = (const float*)d_in[11];
    const float* c1      = (const float*)d_in[12];
    const float* c2      = (const float*)d_in[13];
    const float* gamma   = (const float*)d_in[14];
    const float* beta    = (const float*)d_in[15];
    const float* head_W  = (const float*)d_in[16];
    const float* head_b  = (const float*)d_in[17];
    const float* trend_W = (const float*)d_in[18];
    const float* trend_b = (const float*)d_in[19];
    float* out = (float*)d_out;
    float* ws  = (float*)d_ws;

    unsigned short* seasB  = (unsigned short*)ws;
    unsigned short* trendB = (unsigned short*)(ws + 688128);
    unsigned short* xpB    = (unsigned short*)(ws + 1376256);
    unsigned short* bufAb  = (unsigned short*)(ws + 2924544);
    unsigned short* tmpB16 = (unsigned short*)(ws + 4988928);
    unsigned short* tmp2   = (unsigned short*)(ws + 7053312);
    unsigned short* bufCb  = (unsigned short*)(ws + 9117696);
    float* qF    = ws + 11182080;
    float* Ore_g = qF;
    float* Oim_g = qF + 2031616;
    float* big   = ws + 15310848;
    unsigned short* hidB = (unsigned short*)big;
    float* Xre_g = big;
    float* Xim_g = big + 2031616;
    unsigned short* WqB = (unsigned short*)(ws + 23568384);
    unsigned short* WoB = (unsigned short*)(ws + 23830528);
    unsigned short* c1B = (unsigned short*)(ws + 24092672);
    unsigned short* c2B = (unsigned short*)(ws + 25141248);
    unsigned short* pWB = (unsigned short*)(ws + 26189824);
    float* cosT = ws + 26288128;
    float* sinT = ws + 26290144;
    float* trendout = ws + 26292160;
    float* parts = ws + 26550208;     // 12 * 258048 floats

    auto cdiv = [](int a, int b) { return (a + b - 1) / b; };

    prep_k<<<5321,256,0,stream>>>(Wq, Wo, c1, c2, WqB, WoB, c1B, c2B, patch_W, pWB, cosT, sinT);
    decomp_input_k<<<cdiv(B_*C_*16,256),256,0,stream>>>(x_enc, seasB, trendB);
    patches_k<<<cdiv(B_*L_*384,256),256,0,stream>>>(seasB, xpB);
    trend_mfma<<<42,256,0,stream>>>(trendB, trend_W, trend_b, head_b, trendout);

    gemm_mfma<<<dim3(4,126),256,0,stream>>>(xpB, pWB, patch_b, (float*)nullptr, bufAb, ML, 512, 384, 0);

    for (int l = 0; l < 2; ++l) {
        const unsigned short* WqB_l = WqB + (size_t)l*512*512;
        const unsigned short* WoB_l = WoB + (size_t)l*512*512;
        const unsigned short* c1B_l = c1B + (size_t)l*FF_*D_;
        const unsigned short* c2B_l = c2B + (size_t)l*D_*FF_;
        const float* bq_l = bq + (size_t)l*512;
        const float* bo_l = bo + (size_t)l*512;
        const float* wr_l = four_wr + (size_t)l*H_*DH_*DH_*MODES_;
        const float* wi_l = four_wi + (size_t)l*H_*DH_*DH_*MODES_;

        gemm_mfma<<<dim3(4,126),256,0,stream>>>(bufAb, WqB_l, bq_l, qF, (unsigned short*)nullptr, ML, 512, 512, 0);
        fourier1_k<<<B_*H_,256,0,stream>>>(qF, cosT, sinT, Xre_g, Xim_g);
        fourier2_k<<<H_*MODES_,256,0,stream>>>(Xre_g, Xim_g, wr_l, wi_l, Ore_g, Oim_g);
        fourier3_k<<<B_*H_,256,0,stream>>>(Ore_g, Oim_g, cosT, sinT, tmpB16);
        gemm_mfma<<<dim3(4,126),256,0,stream>>>(tmpB16, WoB_l, bo_l, (float*)nullptr, tmp2, ML, 512, 512, 0);
        decomp_add_k<<<cdiv(B_*D_,256),256,0,stream>>>(bufAb, tmp2, bufCb);
        gemm_mfma<<<dim3(16,126),256,0,stream>>>(bufCb, c1B_l, (const float*)nullptr, (float*)nullptr, hidB, ML, FF_, 512, 1);
        gemm_mfma<<<dim3(4,126),256,0,stream>>>(hidB, c2B_l, (const float*)nullptr, (float*)nullptr, tmp2, ML, 512, FF_, 0);
        decomp_add_k<<<cdiv(B_*D_,256),256,0,stream>>>(bufCb, tmp2, bufAb);
    }

    ln_colmean_k<<<B_,256,0,stream>>>(bufAb, gamma, beta, tmpB16);
    head_mfma<<<dim3(42,12),256,0,stream>>>(tmpB16, head_W, parts);
    reduce_k<<<cdiv(64512,256),256,0,stream>>>(trendout, parts, out);
}